// Round 11
// baseline (2298.282 us; speedup 1.0000x reference)
//
#include <hip/hip_runtime.h>
#include <hip/hip_bf16.h>
#include <cstdint>
#include <cstddef>

#define DEVI __device__ __forceinline__

typedef short bf16x8 __attribute__((ext_vector_type(8)));
typedef float f32x4 __attribute__((ext_vector_type(4)));

static constexpr int B_ = 8192;
static constexpr int IN_ = 2048;
static constexpr int OUT_ = 1000;

DEVI float bf2f(unsigned short u) { return __uint_as_float(((unsigned int)u) << 16); }
DEVI unsigned short f2bf(float f) {
    unsigned int x = __float_as_uint(f);
    unsigned int r = x + 0x7FFFu + ((x >> 16) & 1u);
    return (unsigned short)(r >> 16);
}

DEVI void gload16(const unsigned short* g, unsigned short* l) {
    __builtin_amdgcn_global_load_lds((const __attribute__((address_space(1))) void*)g,
                                     (__attribute__((address_space(3))) void*)l, 16, 0, 0);
}

// XCD row-chunk swizzle (proven R3->R4): each XCD owns contiguous row-tiles.
DEVI void xcd_swizzle(int& bx, int& by) {
    const int NX = gridDim.x, NY = gridDim.y;
    if ((NY & 7) == 0) {
        const int NYc = NY >> 3;
        const int d = by * NX + bx;
        const int xcd = d & 7, idx = d >> 3;
        by = xcd * NYc + (idx % NYc);
        bx = idx / NYc;
    }
}

// fast tanh via hw exp: tanh(x) = 1 - 2/(e^{2x}+1), clamped
DEVI float fast_tanh(float x) {
    float xc = fminf(fmaxf(x, -10.f), 10.f);
    float e = __expf(2.f * xc);
    return 1.f - 2.f / (e + 1.f);
}

// ACT: 0=none 1=silu 2=gelu(exact) 3=mish 4=relu 5=tanh
template <int ACT> DEVI float apply_act(float v) {
    if constexpr (ACT == 1) return v / (1.f + __expf(-v));
    else if constexpr (ACT == 2) return 0.5f * v * (1.f + erff(v * 0.70710678118654752f));
    else if constexpr (ACT == 3) {
        float p = __expf(fminf(v, 20.f));
        float sp = (v > 20.f) ? v : __logf(1.f + p);
        return v * fast_tanh(sp);
    } else if constexpr (ACT == 4) return fmaxf(v, 0.f);
    else if constexpr (ACT == 5) return fast_tanh(v);
    else return v;
}

// ---------------- fp32 -> bf16 conversion ----------------
__global__ __launch_bounds__(256) void cvt_kernel(const float* __restrict__ in,
                                                  unsigned short* __restrict__ out, int n4) {
    int stride = gridDim.x * blockDim.x;
    for (int i = blockIdx.x * blockDim.x + threadIdx.x; i < n4; i += stride) {
        float4 v = ((const float4*)in)[i];
        ushort4 o;
        o.x = f2bf(v.x); o.y = f2bf(v.y); o.z = f2bf(v.z); o.w = f2bf(v.w);
        ((ushort4*)out)[i] = o;
    }
}

// dom_experts_w [4*1000][2048] f32 -> padded stacked [4*1024][2048] bf16 (pad rows zero)
__global__ __launch_bounds__(256) void cvt_dom_kernel(const float* __restrict__ in,
                                                      unsigned short* __restrict__ out) {
    const int total = 4096 * (IN_ / 4);
    int stride = gridDim.x * blockDim.x;
    for (int i = blockIdx.x * blockDim.x + threadIdx.x; i < total; i += stride) {
        int orow = i >> 9;
        int oc4 = i & 511;
        int s = orow >> 10, r = orow & 1023;
        ushort4 o = {0, 0, 0, 0};
        if (r < 1000) {
            float4 v = ((const float4*)(in + ((size_t)(s * 1000 + r)) * IN_))[oc4];
            o.x = f2bf(v.x); o.y = f2bf(v.y); o.z = f2bf(v.z); o.w = f2bf(v.w);
        }
        ((ushort4*)out)[i] = o;
    }
}

// ---------------- per-row LN stats (+ optional bf16 materialization) ----------------
__global__ __launch_bounds__(256) void stats_kernel(const float* __restrict__ x,
                                                    const float* __restrict__ g,
                                                    const float* __restrict__ bta,
                                                    float* __restrict__ mu,
                                                    float* __restrict__ rstd,
                                                    unsigned short* __restrict__ xb,
                                                    unsigned short* __restrict__ hb,
                                                    unsigned short* __restrict__ shb,
                                                    const int wX, const int wH, const int wS) {
    const int r = blockIdx.x;
    const int t = threadIdx.x;
    const float* xr = x + (size_t)r * IN_;
    float v[8];
    float s = 0.f, q = 0.f;
#pragma unroll
    for (int i = 0; i < 8; ++i) {
        v[i] = xr[t + i * 256];
        s += v[i];
        q += v[i] * v[i];
    }
#pragma unroll
    for (int off = 32; off > 0; off >>= 1) {
        s += __shfl_down(s, off);
        q += __shfl_down(q, off);
    }
    __shared__ float ss[4], qq[4];
    if ((t & 63) == 0) { ss[t >> 6] = s; qq[t >> 6] = q; }
    __syncthreads();
    s = ss[0] + ss[1] + ss[2] + ss[3];
    q = qq[0] + qq[1] + qq[2] + qq[3];
    const float mean = s * (1.f / IN_);
    const float var = q * (1.f / IN_) - mean * mean;
    const float rs = rsqrtf(var + 1e-5f);
    if (t == 0) { mu[r] = mean; rstd[r] = rs; }
#pragma unroll
    for (int i = 0; i < 8; ++i) {
        int c = t + i * 256;
        if (wX) xb[(size_t)r * IN_ + c] = f2bf(v[i]);
        if (wH | wS) {
            float h = (v[i] - mean) * rs * g[c] + bta[c];
            if (wH) hb[(size_t)r * IN_ + c] = f2bf(h);
            if (wS) shb[(size_t)r * IN_ + c] = f2bf(h / (1.f + __expf(-h)));
        }
    }
}

// ---------------- routers ----------------
__global__ __launch_bounds__(256) void router_kernel(
    const float* __restrict__ x, const float* __restrict__ mu, const float* __restrict__ rstd,
    const float* __restrict__ g, const float* __restrict__ bta,
    const float* __restrict__ rw0, const float* __restrict__ rb0,
    const float* __restrict__ rw1, const float* __restrict__ rb1,
    const float* __restrict__ rw2, const float* __restrict__ rb2,
    const float* __restrict__ rw3, const float* __restrict__ rb3,
    const float* __restrict__ scales, const float* __restrict__ domw,
    const float* __restrict__ domb, float* __restrict__ coeff) {
    const int r = blockIdx.x;
    const int t = threadIdx.x;
    __shared__ float xs[IN_];
    __shared__ float hs[IN_];
    __shared__ float dots[18];
    const float m = mu[r], rs = rstd[r];
#pragma unroll
    for (int i = 0; i < 8; ++i) {
        int c = t + i * 256;
        float xv = x[(size_t)r * IN_ + c];
        xs[c] = xv;
        hs[c] = (xv - m) * rs * g[c] + bta[c];
    }
    __syncthreads();
    const int w = t >> 6, l = t & 63;
    const float* wp[5] = {rw0, rw1, rw2, rw3, domw};
    for (int d = w; d < 18; d += 4) {
        int gidx, row;
        if (d < 2) { gidx = 0; row = d; }
        else if (d < 5) { gidx = 1; row = d - 2; }
        else if (d < 9) { gidx = 2; row = d - 5; }
        else if (d < 14) { gidx = 3; row = d - 9; }
        else { gidx = 4; row = d - 14; }
        const float* wt = wp[gidx] + (size_t)row * IN_;
        const float* src = (gidx == 4) ? hs : xs;
        float p = 0.f;
        for (int i = l; i < IN_; i += 64) p += src[i] * wt[i];
#pragma unroll
        for (int off = 32; off > 0; off >>= 1) p += __shfl_down(p, off);
        if (l == 0) dots[d] = p;
    }
    __syncthreads();
    if (t == 0) {
        const float* rbs[4] = {rb0, rb1, rb2, rb3};
        float c[4] = {0.f, 0.f, 0.f, 0.f};
        int off = 0;
        for (int i = 0; i < 4; ++i) {
            int n = i + 2;
            float lg[5], mx = -1e30f;
            for (int j = 0; j < n; ++j) { lg[j] = dots[off + j] + rbs[i][j]; mx = fmaxf(mx, lg[j]); }
            float den = 0.f;
            for (int j = 0; j < n; ++j) { lg[j] = expf(lg[j] - mx); den += lg[j]; }
            float inv = 1.f / den;
            float sci = scales[i];
            for (int j = 0; j <= i; ++j) c[j] += sci * lg[j] * inv;
            off += n;
        }
        float dl[4], mx = -1e30f;
        for (int k = 0; k < 4; ++k) { dl[k] = dots[14 + k] + domb[k]; mx = fmaxf(mx, dl[k]); }
        float den = 0.f;
        for (int k = 0; k < 4; ++k) { dl[k] = expf(dl[k] - mx); den += dl[k]; }
        float inv = 1.f / den;
        for (int j = 0; j < 4; ++j) coeff[(size_t)r * 8 + j] = c[j];
        for (int k = 0; k < 4; ++k) coeff[(size_t)r * 8 + 4 + k] = dl[k] * inv;
    }
}

// ---------- dom reduce: out[r][c] += zeta * sum_s coeff[r][4+s] * U[r][s*1024+c] ----------
__global__ __launch_bounds__(256) void dom_reduce(
    const unsigned short* __restrict__ U, const float* __restrict__ coeff,
    float* __restrict__ out, const float* __restrict__ zetap) {
    const float zeta = zetap[0];
    const int nGroups = B_ * (OUT_ / 8);  // 8192 * 125
    const int stride = gridDim.x * blockDim.x;
    for (int i = blockIdx.x * blockDim.x + threadIdx.x; i < nGroups; i += stride) {
        const int r = i / 125;
        const int c8 = (i - r * 125) * 8;
        const float w0 = zeta * coeff[(size_t)r * 8 + 4];
        const float w1 = zeta * coeff[(size_t)r * 8 + 5];
        const float w2 = zeta * coeff[(size_t)r * 8 + 6];
        const float w3 = zeta * coeff[(size_t)r * 8 + 7];
        const unsigned short* ur = U + (size_t)r * 4096 + c8;
        bf16x8 p0 = *(const bf16x8*)(ur);
        bf16x8 p1 = *(const bf16x8*)(ur + 1024);
        bf16x8 p2 = *(const bf16x8*)(ur + 2048);
        bf16x8 p3 = *(const bf16x8*)(ur + 3072);
        float* orow = out + (size_t)r * OUT_ + c8;
#pragma unroll
        for (int j = 0; j < 8; ++j) {
            orow[j] += w0 * bf2f((unsigned short)p0[j]) + w1 * bf2f((unsigned short)p1[j]) +
                       w2 * bf2f((unsigned short)p2[j]) + w3 * bf2f((unsigned short)p3[j]);
        }
    }
}

// ============ 256x256 4-sub-phase bf16 GEMM (R7-verified; + nt-store epilogue) ============
template <int ACT>
__global__ __launch_bounds__(512, 2) void gemm8p(
    const unsigned short* __restrict__ A, const unsigned short* __restrict__ Bw,
    unsigned short* __restrict__ outB, const int N, const int K) {
    extern __shared__ unsigned short lds[];
    const int t = threadIdx.x;
    const int l = t & 63, w = t >> 6;
    const int wr = w >> 2, wc = w & 3;
    int bx = blockIdx.x, by = blockIdx.y;
    xcd_swizzle(bx, by);
    const int rowBase = by * 256, colBase = bx * 256;

    const int lr = l >> 3;
    const int lcs = (((l & 7) ^ lr) << 3);
    const unsigned short* aSrc[4];
    const unsigned short* bSrc[4];
    int aDst[4], bDst[4];
#pragma unroll
    for (int j = 0; j < 4; ++j) {
        const int h = j >> 1, ci = w * 2 + (j & 1);
        aSrc[j] = A + (size_t)(rowBase + h * 128 + ci * 8 + lr) * K + lcs;
        bSrc[j] = Bw + (size_t)(colBase + h * 128 + ci * 8 + lr) * K + lcs;
        aDst[j] = h * 8192 + ci * 512;
        bDst[j] = 16384 + h * 8192 + ci * 512;
    }

    const int fr = l & 15, fg = l >> 4;
    const int kx0 = ((fg ^ (fr & 7)) << 3);
    const int kx1 = (((4 + fg) ^ (fr & 7)) << 3);
    const int aRow = (wr * 128 + fr) * 64;
    const int bRow = 16384 + (wc * 64 + fr) * 64;

    f32x4 acc[8][4];
#pragma unroll
    for (int m = 0; m < 8; ++m)
#pragma unroll
        for (int n = 0; n < 4; ++n) acc[m][n] = (f32x4){0.f, 0.f, 0.f, 0.f};

    const int nt = K >> 6;

#pragma unroll
    for (int j = 0; j < 4; ++j) gload16(aSrc[j], &lds[aDst[j]]);
#pragma unroll
    for (int j = 0; j < 4; ++j) gload16(bSrc[j], &lds[bDst[j]]);

    bf16x8 aF[4][2], bF[2][2];

#define LOAD_A(mh)                                                                         \
    _Pragma("unroll") for (int m = 0; m < 4; ++m) {                                        \
        aF[m][0] = *(const bf16x8*)&lds[bo + aRow + ((mh)*64 + m * 16) * 64 + kx0];        \
        aF[m][1] = *(const bf16x8*)&lds[bo + aRow + ((mh)*64 + m * 16) * 64 + kx1];        \
    }
#define LOAD_B(nh)                                                                         \
    _Pragma("unroll") for (int n = 0; n < 2; ++n) {                                        \
        bF[n][0] = *(const bf16x8*)&lds[bo + bRow + ((nh)*32 + n * 16) * 64 + kx0];        \
        bF[n][1] = *(const bf16x8*)&lds[bo + bRow + ((nh)*32 + n * 16) * 64 + kx1];        \
    }
#define MFMA_PHASE(mh, nh)                                                                 \
    __builtin_amdgcn_s_setprio(1);                                                         \
    _Pragma("unroll") for (int m = 0; m < 4; ++m)                                          \
        _Pragma("unroll") for (int n = 0; n < 2; ++n) {                                    \
            acc[(mh)*4 + m][(nh)*2 + n] = __builtin_amdgcn_mfma_f32_16x16x32_bf16(         \
                aF[m][0], bF[n][0], acc[(mh)*4 + m][(nh)*2 + n], 0, 0, 0);                 \
            acc[(mh)*4 + m][(nh)*2 + n] = __builtin_amdgcn_mfma_f32_16x16x32_bf16(         \
                aF[m][1], bF[n][1], acc[(mh)*4 + m][(nh)*2 + n], 0, 0, 0);                 \
        }                                                                                  \
    __builtin_amdgcn_s_setprio(0);

    for (int ti = 0; ti < nt; ++ti) {
        const int bo = (ti & 1) << 15;
        const int so = bo ^ 32768;
        const int ko = (ti + 1) << 6;
        const bool pre = (ti + 1 < nt);
        asm volatile("s_waitcnt vmcnt(0)" ::: "memory");
        asm volatile("s_barrier" ::: "memory");
        if (pre) {
#pragma unroll
            for (int j = 0; j < 4; ++j) gload16(aSrc[j] + ko, &lds[so + aDst[j]]);
        }
        LOAD_A(0)
        LOAD_B(0)
        MFMA_PHASE(0, 0)
        asm volatile("s_barrier" ::: "memory");
        if (pre) {
#pragma unroll
            for (int j = 0; j < 4; ++j) gload16(bSrc[j] + ko, &lds[so + bDst[j]]);
        }
        LOAD_A(1)
        MFMA_PHASE(1, 0)
        asm volatile("s_barrier" ::: "memory");
        LOAD_B(1)
        MFMA_PHASE(1, 1)
        asm volatile("s_barrier" ::: "memory");
        LOAD_A(0)
        MFMA_PHASE(0, 1)
    }
#undef LOAD_A
#undef LOAD_B
#undef MFMA_PHASE

    // nt stores: U is stream-out, skip L2 allocation (fixes measured write-allocate fetch)
#pragma unroll
    for (int m = 0; m < 8; ++m) {
        const int grow0 = rowBase + wr * 128 + m * 16 + fg * 4;
#pragma unroll
        for (int n = 0; n < 4; ++n) {
            const int gcol = colBase + wc * 64 + n * 16 + fr;
#pragma unroll
            for (int j = 0; j < 4; ++j) {
                float v = apply_act<ACT>(acc[m][n][j]);
                __builtin_nontemporal_store(f2bf(v), &outB[(size_t)(grow0 + j) * N + gcol]);
            }
        }
    }
}

// ============ 128x64-tile BK=64 GEMM (R10 bk64 template, re-tiled for small N) ============
// 4 waves as 2x2; wave-tile 64x32; 1024 blocks at N=1000 -> 4 blocks/CU (latency fix).
// MODE: 0 = write f32 (+bias), 1 = accumulate f32, 2 = write bf16 (nt).
template <int ACT, int MODE, int BIASF>
__global__ __launch_bounds__(256) void gemm_n64(
    const unsigned short* __restrict__ A, const unsigned short* __restrict__ Bw,
    float* __restrict__ outF, unsigned short* __restrict__ outB,
    const float* __restrict__ bias, const float* __restrict__ coeff, const int cidx,
    const float* __restrict__ scalarp, const int N, const int K) {
    __shared__ unsigned short Asm[2][8192];   // 128 x 64
    __shared__ unsigned short Bsm[2][4096];   // 64 x 64
    const int t = threadIdx.x;
    const int l = t & 63;
    const int w = t >> 6;
    const int wr = w >> 1, wc = w & 1;
    int bx = blockIdx.x, by = blockIdx.y;
    xcd_swizzle(bx, by);
    const int rowBase = by * 128;
    const int colBase = bx * 64;

    // staging: A rows w*32..w*32+31 (4 chunks of 8); B rows w*16..w*16+15 (2 chunks).
    // swizzle: LDS[row][c] = G[row][c ^ (row&7)] (row&7 == lr).
    const int lr = l >> 3;
    const int lcs = (((l & 7) ^ lr) << 3);
    const unsigned short* aS[4];
    const unsigned short* bS[2];
    int dstA[4], dstB[2];
#pragma unroll
    for (int i = 0; i < 4; ++i) {
        const int r0 = w * 32 + i * 8;
        aS[i] = A + (size_t)(rowBase + r0 + lr) * K + lcs;
        dstA[i] = r0 * 64;
    }
#pragma unroll
    for (int i = 0; i < 2; ++i) {
        const int r0 = w * 16 + i * 8;
        int br = colBase + r0 + lr; if (br >= N) br = N - 1;
        bS[i] = Bw + (size_t)br * K + lcs;
        dstB[i] = r0 * 64;
    }

    f32x4 acc[4][2];
#pragma unroll
    for (int m = 0; m < 4; ++m)
#pragma unroll
        for (int n = 0; n < 2; ++n) acc[m][n] = (f32x4){0.f, 0.f, 0.f, 0.f};

    const int nK = K >> 6;

    auto stage = [&](int buf, int kt) {
        const int ko = kt << 6;
#pragma unroll
        for (int i = 0; i < 4; ++i) gload16(aS[i] + ko, &Asm[buf][dstA[i]]);
#pragma unroll
        for (int i = 0; i < 2; ++i) gload16(bS[i] + ko, &Bsm[buf][dstB[i]]);
    };

    stage(0, 0);
    __syncthreads();

    const int fr = l & 15;
    const int fg = l >> 4;
    const int kx0 = ((fg ^ (fr & 7)) << 3);
    const int kx1 = (((4 + fg) ^ (fr & 7)) << 3);

    int buf = 0;
    for (int kt = 0; kt < nK; ++kt) {
        if (kt + 1 < nK) stage(buf ^ 1, kt + 1);
        bf16x8 af[4][2], bfr[2][2];
#pragma unroll
        for (int m = 0; m < 4; ++m) {
            const int ar = (wr * 64 + m * 16 + fr) * 64;
            af[m][0] = *(const bf16x8*)&Asm[buf][ar + kx0];
            af[m][1] = *(const bf16x8*)&Asm[buf][ar + kx1];
        }
#pragma unroll
        for (int n = 0; n < 2; ++n) {
            const int br = (wc * 32 + n * 16 + fr) * 64;
            bfr[n][0] = *(const bf16x8*)&Bsm[buf][br + kx0];
            bfr[n][1] = *(const bf16x8*)&Bsm[buf][br + kx1];
        }
#pragma unroll
        for (int m = 0; m < 4; ++m)
#pragma unroll
            for (int n = 0; n < 2; ++n) {
                acc[m][n] = __builtin_amdgcn_mfma_f32_16x16x32_bf16(af[m][0], bfr[n][0], acc[m][n], 0, 0, 0);
                acc[m][n] = __builtin_amdgcn_mfma_f32_16x16x32_bf16(af[m][1], bfr[n][1], acc[m][n], 0, 0, 0);
            }
        __syncthreads();
        buf ^= 1;
    }

    const float scal = scalarp ? scalarp[0] : 1.0f;
#pragma unroll
    for (int m = 0; m < 4; ++m) {
        const int grow0 = rowBase + wr * 64 + m * 16 + fg * 4;
#pragma unroll
        for (int n = 0; n < 2; ++n) {
            const int gcol = colBase + wc * 32 + n * 16 + fr;
            if (gcol < N) {
                float bv = BIASF ? bias[gcol] : 0.f;
#pragma unroll
                for (int j = 0; j < 4; ++j) {
                    const int grow = grow0 + j;
                    float v = acc[m][n][j] + bv;
                    v = apply_act<ACT>(v);
                    float alpha = scal;
                    if (coeff) alpha *= coeff[(size_t)grow * 8 + cidx];
                    v *= alpha;
                    const size_t o = (size_t)grow * N + gcol;
                    if constexpr (MODE == 2) __builtin_nontemporal_store(f2bf(v), &outB[o]);
                    else if constexpr (MODE == 1) outF[o] += v;
                    else outF[o] = v;
                }
            }
        }
    }
}

// ============ bf16 MFMA GEMM, BK=32 128x128 (kept for large-grid dom stage 1) ============
template <int ACT, int MODE, int BIASF>
__global__ __launch_bounds__(256) void gemm_lds(
    const unsigned short* __restrict__ A, const unsigned short* __restrict__ Bw,
    float* __restrict__ outF, unsigned short* __restrict__ outB,
    const float* __restrict__ bias, const float* __restrict__ coeff, const int cidx,
    const float* __restrict__ scalarp, const int N, const int K) {
    __shared__ unsigned short Asm[2][4096];
    __shared__ unsigned short Bsm[2][4096];
    const int t = threadIdx.x;
    const int l = t & 63;
    const int w = t >> 6;
    const int wr = w >> 1, wc = w & 1;
    int bx = blockIdx.x, by = blockIdx.y;
    xcd_swizzle(bx, by);
    const int rowBase = by * 128;
    const int colBase = bx * 128;

    const int lr = l >> 2;
    const int lk = (l & 3) << 3;
    const int ar0 = rowBase + w * 32 + lr;
    const int ar1 = ar0 + 16;
    int br0 = colBase + w * 32 + lr;      if (br0 >= N) br0 = N - 1;
    int br1 = colBase + w * 32 + 16 + lr; if (br1 >= N) br1 = N - 1;
    const unsigned short* pA0 = A + (size_t)ar0 * K + lk;
    const unsigned short* pA1 = A + (size_t)ar1 * K + lk;
    const unsigned short* pB0 = Bw + (size_t)br0 * K + lk;
    const unsigned short* pB1 = Bw + (size_t)br1 * K + lk;
    const int ldsA0 = (w * 32) * 32;
    const int ldsA1 = (w * 32 + 16) * 32;

    f32x4 acc[4][4];
#pragma unroll
    for (int m = 0; m < 4; ++m)
#pragma unroll
        for (int n = 0; n < 4; ++n) acc[m][n] = (f32x4){0.f, 0.f, 0.f, 0.f};

    const int nK = K >> 5;

    auto stage = [&](int buf, int kt) {
        const int ko = kt << 5;
        gload16(pA0 + ko, &Asm[buf][ldsA0]);
        gload16(pA1 + ko, &Asm[buf][ldsA1]);
        gload16(pB0 + ko, &Bsm[buf][ldsA0]);
        gload16(pB1 + ko, &Bsm[buf][ldsA1]);
    };

    stage(0, 0);
    __syncthreads();

    const int fr = l & 15;
    const int fg = l >> 4;
    const int aoff = (wr * 64 + fr) * 32 + fg * 8;
    const int boff = (wc * 64 + fr) * 32 + fg * 8;

    int buf = 0;
    for (int kt = 0; kt < nK; ++kt) {
        if (kt + 1 < nK) stage(buf ^ 1, kt + 1);
        bf16x8 af[4], bfr[4];
#pragma unroll
        for (int m = 0; m < 4; ++m) af[m] = *(const bf16x8*)&Asm[buf][aoff + m * 512];
#pragma unroll
        for (int n = 0; n < 4; ++n) bfr[n] = *(const bf16x8*)&Bsm[buf][boff + n * 512];
#pragma unroll
        for (int m = 0; m < 4; ++m)
#pragma unroll
            for (int n = 0; n < 4; ++n)
                acc[m][n] = __builtin_amdgcn_mfma_f32_16x16x32_bf16(af[m], bfr[n], acc[m][n], 0, 0, 0);
        __syncthreads();
        buf ^= 1;
    }

    const float scal = scalarp ? scalarp[0] : 1.0f;
#pragma unroll
    for (int m = 0; m < 4; ++m) {
        const int grow0 = rowBase + wr * 64 + m * 16 + fg * 4;
#pragma unroll
        for (int n = 0; n < 4; ++n) {
            const int gcol = colBase + wc * 64 + n * 16 + fr;
            if (gcol < N) {
                float bv = BIASF ? bias[gcol] : 0.f;
#pragma unroll
                for (int j = 0; j < 4; ++j) {
                    const int grow = grow0 + j;
                    float v = acc[m][n][j] + bv;
                    v = apply_act<ACT>(v);
                    float alpha = scal;
                    if (coeff) alpha *= coeff[(size_t)grow * 8 + cidx];
                    v *= alpha;
                    const size_t o = (size_t)grow * N + gcol;
                    if constexpr (MODE == 2) __builtin_nontemporal_store(f2bf(v), &outB[o]);
                    else if constexpr (MODE == 1) outF[o] += v;
                    else outF[o] = v;
                }
            }
        }
    }
}

// ---------------- generic (fallback-tier) GEMM: reg-staged, fp32-capable sources ----------------
template <int ASRC, int ASIL, int BSRC, int ACT, int OUTBF, int ACCUM, int BIASF>
__global__ __launch_bounds__(256) void gemm_bt(
    const void* __restrict__ Ap, const void* __restrict__ Bp,
    float* __restrict__ outF, unsigned short* __restrict__ outB,
    const float* __restrict__ bias, const float* __restrict__ coeff, const int cidx,
    const float* __restrict__ scalarp,
    const float* __restrict__ muP, const float* __restrict__ rsP,
    const float* __restrict__ lng, const float* __restrict__ lnb,
    const int N, const int K) {
    __shared__ unsigned short Asm[2][4096];
    __shared__ unsigned short Bsm[2][4096];
    const int t = threadIdx.x;
    const int l = t & 63;
    const int w = t >> 6;
    const int wr = w >> 1, wc = w & 1;
    int bx = blockIdx.x, by = blockIdx.y;
    xcd_swizzle(bx, by);
    const int rowBase = by * 128;
    const int colBase = bx * 128;

    const int srow = t >> 2;
    const int skol = (t & 3) << 3;
    const int arow0 = rowBase + srow;
    const int arow1 = arow0 + 64;
    int br0 = colBase + srow;        if (br0 >= N) br0 = N - 1;
    int br1 = colBase + srow + 64;   if (br1 >= N) br1 = N - 1;

    float mu0 = 0.f, rs0 = 1.f, mu1 = 0.f, rs1 = 1.f;
    if constexpr (ASRC == 2) {
        mu0 = muP[arow0]; rs0 = rsP[arow0];
        mu1 = muP[arow1]; rs1 = rsP[arow1];
    }

    auto ldA = [&](int row, float mu_, float rs_, int k0) -> bf16x8 {
        if constexpr (ASRC == 0) {
            bf16x8 v = *(const bf16x8*)((const unsigned short*)Ap + (size_t)row * K + k0);
            if constexpr (ASIL) {
                bf16x8 r;
#pragma unroll
                for (int i = 0; i < 8; ++i) {
                    float f = bf2f((unsigned short)v[i]);
                    r[i] = (short)f2bf(f / (1.f + __expf(-f)));
                }
                return r;
            }
            return v;
        } else {
            const float* f = (const float*)Ap + (size_t)row * K + k0;
            float4 v0 = *(const float4*)f;
            float4 v1 = *(const float4*)(f + 4);
            float vv[8] = {v0.x, v0.y, v0.z, v0.w, v1.x, v1.y, v1.z, v1.w};
            if constexpr (ASRC == 2) {
                float4 g0 = *(const float4*)(lng + k0), g1 = *(const float4*)(lng + k0 + 4);
                float4 b0 = *(const float4*)(lnb + k0), b1 = *(const float4*)(lnb + k0 + 4);
                float gg[8] = {g0.x, g0.y, g0.z, g0.w, g1.x, g1.y, g1.z, g1.w};
                float bb[8] = {b0.x, b0.y, b0.z, b0.w, b1.x, b1.y, b1.z, b1.w};
#pragma unroll
                for (int i = 0; i < 8; ++i) vv[i] = (vv[i] - mu_) * rs_ * gg[i] + bb[i];
            }
            if constexpr (ASIL) {
#pragma unroll
                for (int i = 0; i < 8; ++i) vv[i] = vv[i] / (1.f + __expf(-vv[i]));
            }
            bf16x8 r;
#pragma unroll
            for (int i = 0; i < 8; ++i) r[i] = (short)f2bf(vv[i]);
            return r;
        }
    };
    auto ldB = [&](int row, int k0) -> bf16x8 {
        if constexpr (BSRC == 0) {
            return *(const bf16x8*)((const unsigned short*)Bp + (size_t)row * K + k0);
        } else {
            const float* f = (const float*)Bp + (size_t)row * K + k0;
            float4 v0 = *(const float4*)f;
            float4 v1 = *(const float4*)(f + 4);
            float vv[8] = {v0.x, v0.y, v0.z, v0.w, v1.x, v1.y, v1.z, v1.w};
            bf16x8 r;
#pragma unroll
            for (int i = 0; i < 8; ++i) r[i] = (short)f2bf(vv[i]);
            return r;
        }
    };

    const int wo = t * 8;

    f32x4 acc[4][4];
#pragma unroll
    for (int m = 0; m < 4; ++m)
#pragma unroll
        for (int n = 0; n < 4; ++n) acc[m][n] = (f32x4){0.f, 0.f, 0.f, 0.f};

    const int nK = K >> 5;

    bf16x8 a0 = ldA(arow0, mu0, rs0, skol);
    bf16x8 a1 = ldA(arow1, mu1, rs1, skol);
    bf16x8 b0 = ldB(br0, skol);
    bf16x8 b1 = ldB(br1, skol);
    *(bf16x8*)&Asm[0][wo] = a0; *(bf16x8*)&Asm[0][wo + 2048] = a1;
    *(bf16x8*)&Bsm[0][wo] = b0; *(bf16x8*)&Bsm[0][wo + 2048] = b1;
    __syncthreads();

    const int fr = l & 15;
    const int fg = l >> 4;
    const int aoff = (wr * 64 + fr) * 32 + fg * 8;
    const int boff = (wc * 64 + fr) * 32 + fg * 8;

    for (int kt = 0; kt < nK; ++kt) {
        const int cur = kt & 1;
        if (kt + 1 < nK) {
            const int ko = ((kt + 1) << 5) + skol;
            a0 = ldA(arow0, mu0, rs0, ko);
            a1 = ldA(arow1, mu1, rs1, ko);
            b0 = ldB(br0, ko);
            b1 = ldB(br1, ko);
        }
        bf16x8 af[4], bfr[4];
#pragma unroll
        for (int m = 0; m < 4; ++m) af[m] = *(const bf16x8*)&Asm[cur][aoff + m * 512];
#pragma unroll
        for (int n = 0; n < 4; ++n) bfr[n] = *(const bf16x8*)&Bsm[cur][boff + n * 512];
#pragma unroll
        for (int m = 0; m < 4; ++m)
#pragma unroll
            for (int n = 0; n < 4; ++n)
                acc[m][n] = __builtin_amdgcn_mfma_f32_16x16x32_bf16(af[m], bfr[n], acc[m][n], 0, 0, 0);
        if (kt + 1 < nK) {
            __syncthreads();
            const int nxt = cur ^ 1;
            *(bf16x8*)&Asm[nxt][wo] = a0; *(bf16x8*)&Asm[nxt][wo + 2048] = a1;
            *(bf16x8*)&Bsm[nxt][wo] = b0; *(bf16x8*)&Bsm[nxt][wo + 2048] = b1;
            __syncthreads();
        }
    }

    const float scal = scalarp ? scalarp[0] : 1.0f;
#pragma unroll
    for (int m = 0; m < 4; ++m) {
        const int grow0 = rowBase + wr * 64 + m * 16 + fg * 4;
#pragma unroll
        for (int n = 0; n < 4; ++n) {
            const int gcol = colBase + wc * 64 + n * 16 + fr;
            if (gcol < N) {
                float bv = BIASF ? bias[gcol] : 0.f;
#pragma unroll
                for (int j = 0; j < 4; ++j) {
                    const int grow = grow0 + j;
                    float v = acc[m][n][j] + bv;
                    v = apply_act<ACT>(v);
                    float alpha = scal;
                    if (coeff) alpha *= coeff[(size_t)grow * 8 + cidx];
                    v *= alpha;
                    const size_t o = (size_t)grow * N + gcol;
                    if (OUTBF) outB[o] = f2bf(v);
                    else if (ACCUM) outF[o] += v;
                    else outF[o] = v;
                }
            }
        }
    }
}

static inline void cvt(const float* in, unsigned short* out, size_t n, hipStream_t s) {
    int n4 = (int)(n >> 2);
    int blocks = (n4 + 255) / 256;
    if (blocks > 4096) blocks = 4096;
    cvt_kernel<<<blocks, 256, 0, s>>>(in, out, n4);
}

extern "C" void kernel_launch(void* const* d_in, const int* in_sizes, int n_in,
                              void* d_out, int out_size, void* d_ws, size_t ws_size,
                              hipStream_t stream) {
    (void)in_sizes; (void)n_in; (void)out_size;
    const float* x = (const float*)d_in[0];
    const float* W = (const float*)d_in[1];
    const float* bvec = (const float*)d_in[2];
    const float* up_w[4] = {(const float*)d_in[3], (const float*)d_in[7], (const float*)d_in[11], (const float*)d_in[15]};
    const float* down_w[4] = {(const float*)d_in[4], (const float*)d_in[8], (const float*)d_in[12], (const float*)d_in[16]};
    const float* r_w[4] = {(const float*)d_in[5], (const float*)d_in[9], (const float*)d_in[13], (const float*)d_in[17]};
    const float* r_b[4] = {(const float*)d_in[6], (const float*)d_in[10], (const float*)d_in[14], (const float*)d_in[18]};
    const float* scales = (const float*)d_in[19];
    const float* ln_g = (const float*)d_in[20];
    const float* ln_b = (const float*)d_in[21];
    const float* dom_rw = (const float*)d_in[22];
    const float* dom_rb = (const float*)d_in[23];
    const float* dom_ew = (const float*)d_in[24];
    const float* cal_w = (const float*)d_in[25];
    const float* cal_b = (const float*)d_in[26];
    const float* rg_w1 = (const float*)d_in[27];
    const float* rg_w2 = (const float*)d_in[28];
    const float* rg_b2 = (const float*)d_in[29];
    const float* zeta = (const float*)d_in[30];
    const float* theta = (const float*)d_in[31];
    const float* lam = (const float*)d_in[32];
    float* out = (float*)d_out;

    const int E[4] = {2048, 4096, 6144, 8192};
    auto al = [](size_t v) { return (v + 255) & ~(size_t)255; };

    size_t fastNeed = al((size_t)B_ * 8 * 4) + 2 * al((size_t)B_ * 4) +
                      2 * al((size_t)B_ * IN_ * 2) +
                      al((size_t)OUT_ * IN_ * 2) +
                      al((size_t)4096 * IN_ * 2) +
                      al((size_t)OUT_ * IN_ * 2) +
                      al((size_t)512 * IN_ * 2) + al((size_t)OUT_ * 512 * 2) +
                      al((size_t)B_ * 8192 * 2) + al((size_t)B_ * 512 * 2);
    for (int j = 0; j < 4; ++j)
        fastNeed += al((size_t)E[j] * IN_ * 2) + al((size_t)OUT_ * E[j] * 2);

    char* p = (char*)d_ws;
    auto alloc = [&](size_t bytes) { char* r = p; p += (bytes + 255) & ~(size_t)255; return r; };

    const int NT_OUT = (OUT_ + 127) / 128;   // 8  (128-col tiles)
    const int NT64 = (OUT_ + 63) / 64;       // 16 (64-col tiles)
    const int MT = B_ / 128;                 // 64

    if (ws_size >= fastNeed) {
        // ================= FAST PATH =================
        float* coeff = (float*)alloc((size_t)B_ * 8 * 4);
        float* muP = (float*)alloc((size_t)B_ * 4);
        float* rsP = (float*)alloc((size_t)B_ * 4);
        unsigned short* xb = (unsigned short*)alloc((size_t)B_ * IN_ * 2);
        unsigned short* shb = (unsigned short*)alloc((size_t)B_ * IN_ * 2);
        unsigned short* Wb = (unsigned short*)alloc((size_t)OUT_ * IN_ * 2);
        unsigned short* domN = (unsigned short*)alloc((size_t)4096 * IN_ * 2);
        unsigned short* calb = (unsigned short*)alloc((size_t)OUT_ * IN_ * 2);
        unsigned short* rg1b = (unsigned short*)alloc((size_t)512 * IN_ * 2);
        unsigned short* rg2b = (unsigned short*)alloc((size_t)OUT_ * 512 * 2);
        unsigned short* U = (unsigned short*)alloc((size_t)B_ * 8192 * 2);
        unsigned short* T = (unsigned short*)alloc((size_t)B_ * 512 * 2);
        unsigned short* upb[4];
        unsigned short* downb[4];
        for (int j = 0; j < 4; ++j) {
            upb[j] = (unsigned short*)alloc((size_t)E[j] * IN_ * 2);
            downb[j] = (unsigned short*)alloc((size_t)OUT_ * E[j] * 2);
        }
        unsigned short* hbU = U;  // h bf16 borrows U until dom-partial overwrites it

        hipFuncSetAttribute((const void*)gemm8p<1>, hipFuncAttributeMaxDynamicSharedMemorySize, 131072);
        hipFuncSetAttribute((const void*)gemm8p<2>, hipFuncAttributeMaxDynamicSharedMemorySize, 131072);
        hipFuncSetAttribute((const void*)gemm8p<3>, hipFuncAttributeMaxDynamicSharedMemorySize, 131072);
        hipFuncSetAttribute((const void*)gemm8p<4>, hipFuncAttributeMaxDynamicSharedMemorySize, 131072);

        // weight conversions
        cvt(W, Wb, (size_t)OUT_ * IN_, stream);
        cvt_dom_kernel<<<4096, 256, 0, stream>>>(dom_ew, domN);
        cvt(cal_w, calb, (size_t)OUT_ * IN_, stream);
        cvt(rg_w1, rg1b, (size_t)512 * IN_, stream);
        cvt(rg_w2, rg2b, (size_t)OUT_ * 512, stream);
        for (int j = 0; j < 4; ++j) {
            cvt(up_w[j], upb[j], (size_t)E[j] * IN_, stream);
            cvt(down_w[j], downb[j], (size_t)OUT_ * E[j], stream);
        }

        // stats (xb, h -> U scratch, silu(h)) + router coeffs
        stats_kernel<<<B_, 256, 0, stream>>>(x, ln_g, ln_b, muP, rsP, xb, hbU, shb, 1, 1, 1);
        router_kernel<<<B_, 256, 0, stream>>>(x, muP, rsP, ln_g, ln_b,
                                              r_w[0], r_b[0], r_w[1], r_b[1], r_w[2], r_b[2],
                                              r_w[3], r_b[3], scales, dom_rw, dom_rb, coeff);

        // base: out = x @ W^T + b (full write, clears poison)
        gemm_n64<0, 0, 1><<<dim3(NT64, MT), 256, 0, stream>>>(
            xb, Wb, out, nullptr, bvec, nullptr, 0, nullptr, OUT_, IN_);

        // calib: out += theta * tanh(h @ calib^T + calib_b)  (reads h from U, before dom clobbers)
        gemm_n64<5, 1, 1><<<dim3(NT64, MT), 256, 0, stream>>>(
            hbU, calb, out, nullptr, cal_b, nullptr, 0, theta, OUT_, IN_);

        // dom stage 1: partials U[8192][4096] = shb @ domN^T (bf16 nt-store, 2048 blocks)
        gemm_lds<0, 2, 0><<<dim3(32, MT), 256, 0, stream>>>(
            shb, domN, nullptr, U, nullptr, nullptr, 0, nullptr, 4096, IN_);
        // dom stage 2: out += zeta * sum_s w_s[row] * U[row][s*1024+c]
        dom_reduce<<<2048, 256, 0, stream>>>(U, coeff, out, zeta);

        // branches: U = act_j(x @ up_j^T) via 256^2 kernel (nt-store); downs accumulate (n64)
        gemm8p<1><<<dim3(E[0] / 256, B_ / 256), 512, 131072, stream>>>(xb, upb[0], U, E[0], IN_);
        gemm_n64<0, 1, 0><<<dim3(NT64, MT), 256, 0, stream>>>(
            U, downb[0], out, nullptr, nullptr, coeff, 0, nullptr, OUT_, E[0]);
        gemm8p<2><<<dim3(E[1] / 256, B_ / 256), 512, 131072, stream>>>(xb, upb[1], U, E[1], IN_);
        gemm_n64<0, 1, 0><<<dim3(NT64, MT), 256, 0, stream>>>(
            U, downb[1], out, nullptr, nullptr, coeff, 1, nullptr, OUT_, E[1]);
        gemm8p<3><<<dim3(E[2] / 256, B_ / 256), 512, 131072, stream>>>(xb, upb[2], U, E[2], IN_);
        gemm_n64<0, 1, 0><<<dim3(NT64, MT), 256, 0, stream>>>(
            U, downb[2], out, nullptr, nullptr, coeff, 2, nullptr, OUT_, E[2]);
        gemm8p<4><<<dim3(E[3] / 256, B_ / 256), 512, 131072, stream>>>(xb, upb[3], U, E[3], IN_);
        gemm_n64<0, 1, 0><<<dim3(NT64, MT), 256, 0, stream>>>(
            U, downb[3], out, nullptr, nullptr, coeff, 3, nullptr, OUT_, E[3]);

        // reason: T = silu(x @ rg1^T); out += lambda * tanh(T @ rg2^T + rg_b2)
        gemm_n64<1, 2, 0><<<dim3(8, MT), 256, 0, stream>>>(
            xb, rg1b, nullptr, T, nullptr, nullptr, 0, nullptr, 512, IN_);
        gemm_n64<5, 1, 1><<<dim3(NT64, MT), 256, 0, stream>>>(
            T, rg2b, out, nullptr, rg_b2, nullptr, 0, lam, OUT_, 512);
        return;
    }

    // ================= FALLBACK TIERS (verified R2 path) =================
    const size_t S_coeff = al((size_t)B_ * 8 * 4);
    const size_t S_mu = al((size_t)B_ * 4);
    const size_t S_act = al((size_t)B_ * IN_ * 2);
    size_t S_W = al((size_t)OUT_ * IN_ * 2) + al((size_t)4 * OUT_ * IN_ * 2) +
                 al((size_t)OUT_ * IN_ * 2) + al((size_t)512 * IN_ * 2) + al((size_t)OUT_ * 512 * 2);
    for (int j = 0; j < 4; ++j) S_W += al((size_t)E[j] * IN_ * 2) + al((size_t)OUT_ * E[j] * 2);

    auto needOf = [&](bool bfl, bool cwl, int ch) {
        size_t n = S_coeff + 2 * S_mu;
        if (bfl) n += 3 * S_act;
        if (cwl) n += S_W;
        n += al((size_t)ch * 8192 * 2) + al((size_t)ch * 512 * 2);
        return n;
    };
    bool bf = false, cw = false;
    int CH = 512;
    {
        const bool cb[7] = {true, true, true, true, true, true, false};
        const bool cc[7] = {true, true, true, false, false, false, false};
        const int  cch[7] = {8192, 4096, 2048, 4096, 2048, 512, 512};
        for (int i = 0; i < 7; ++i) {
            if (needOf(cb[i], cc[i], cch[i]) <= ws_size || i == 6) {
                bf = cb[i]; cw = cc[i]; CH = cch[i];
                break;
            }
        }
    }

    float* coeff = (float*)alloc((size_t)B_ * 8 * 4);
    float* muP = (float*)alloc((size_t)B_ * 4);
    float* rsP = (float*)alloc((size_t)B_ * 4);
    unsigned short *xb = nullptr, *hb = nullptr, *shb = nullptr;
    if (bf) {
        xb = (unsigned short*)alloc((size_t)B_ * IN_ * 2);
        hb = (unsigned short*)alloc((size_t)B_ * IN_ * 2);
        shb = (unsigned short*)alloc((size_t)B_ * IN_ * 2);
    }
    unsigned short *Wb = nullptr, *upb[4] = {}, *downb[4] = {}, *domb_ = nullptr,
                   *calb = nullptr, *rg1b = nullptr, *rg2b = nullptr;
    if (cw) {
        Wb = (unsigned short*)alloc((size_t)OUT_ * IN_ * 2);
        domb_ = (unsigned short*)alloc((size_t)4 * OUT_ * IN_ * 2);
        calb = (unsigned short*)alloc((size_t)OUT_ * IN_ * 2);
        rg1b = (unsigned short*)alloc((size_t)512 * IN_ * 2);
        rg2b = (unsigned short*)alloc((size_t)OUT_ * 512 * 2);
        for (int j = 0; j < 4; ++j) {
            upb[j] = (unsigned short*)alloc((size_t)E[j] * IN_ * 2);
            downb[j] = (unsigned short*)alloc((size_t)OUT_ * E[j] * 2);
        }
    }
    unsigned short* U = (unsigned short*)alloc((size_t)CH * 8192 * 2);
    unsigned short* T = (unsigned short*)alloc((size_t)CH * 512 * 2);

    if (cw) {
        cvt(W, Wb, (size_t)OUT_ * IN_, stream);
        for (int j = 0; j < 4; ++j) {
            cvt(up_w[j], upb[j], (size_t)E[j] * IN_, stream);
            cvt(down_w[j], downb[j], (size_t)OUT_ * E[j], stream);
        }
        cvt(dom_ew, domb_, (size_t)4 * OUT_ * IN_, stream);
        cvt(cal_w, calb, (size_t)OUT_ * IN_, stream);
        cvt(rg_w1, rg1b, (size_t)512 * IN_, stream);
        cvt(rg_w2, rg2b, (size_t)OUT_ * 512, stream);
    }

    stats_kernel<<<B_, 256, 0, stream>>>(x, ln_g, ln_b, muP, rsP, xb, hb, shb,
                                         bf ? 1 : 0, bf ? 1 : 0, bf ? 1 : 0);
    router_kernel<<<B_, 256, 0, stream>>>(x, muP, rsP, ln_g, ln_b,
                                          r_w[0], r_b[0], r_w[1], r_b[1], r_w[2], r_b[2],
                                          r_w[3], r_b[3], scales, dom_rw, dom_rb, coeff);

#define GARG(A, BW, OF, OB, BI, CF, CI, SC, MU, NN, KK) \
    (const void*)(A), (const void*)(BW), OF, OB, BI, CF, CI, SC, MU, rsP, ln_g, ln_b, NN, KK
#define LX(ACT, OUTBF, ACCUM, BIASF, GRID, Abf, Af, Bb, Bf, OF, OB, BI, CF, CI, SC, MU, NN, KK)         \
    do {                                                                                                \
        if (bf) {                                                                                       \
            if (cw) gemm_bt<0, 0, 0, ACT, OUTBF, ACCUM, BIASF><<<GRID, 256, 0, stream>>>(               \
                GARG(Abf, Bb, OF, OB, BI, CF, CI, SC, MU, NN, KK));                                     \
            else gemm_bt<0, 0, 1, ACT, OUTBF, ACCUM, BIASF><<<GRID, 256, 0, stream>>>(                  \
                GARG(Abf, Bf, OF, OB, BI, CF, CI, SC, MU, NN, KK));                                     \
        } else gemm_bt<1, 0, 1, ACT, OUTBF, ACCUM, BIASF><<<GRID, 256, 0, stream>>>(                    \
                GARG(Af, Bf, OF, OB, BI, CF, CI, SC, MU, NN, KK));                                      \
    } while (0)
#define LD(ACT, OUTBF, ACCUM, BIASF, GRID, A, Bb, Bf, OF, OB, BI, CF, CI, SC, NN, KK)                   \
    do {                                                                                                \
        if (cw) gemm_bt<0, 0, 0, ACT, OUTBF, ACCUM, BIASF><<<GRID, 256, 0, stream>>>(                   \
            GARG(A, Bb, OF, OB, BI, CF, CI, SC, muP, NN, KK));                                          \
        else gemm_bt<0, 0, 1, ACT, OUTBF, ACCUM, BIASF><<<GRID, 256, 0, stream>>>(                      \
            GARG(A, Bf, OF, OB, BI, CF, CI, SC, muP, NN, KK));                                          \
    } while (0)

    LX(0, 0, 0, 1, dim3(NT_OUT, MT), xb, x, Wb, W, out, nullptr, bvec, (const float*)nullptr, 0,
       (const float*)nullptr, muP, OUT_, IN_);

    for (int k = 0; k < 4; ++k) {
        const unsigned short* Bb = cw ? domb_ + (size_t)k * OUT_ * IN_ : nullptr;
        const float* Bf = dom_ew + (size_t)k * OUT_ * IN_;
        if (bf) {
            if (cw) gemm_bt<0, 0, 0, 0, 0, 1, 0><<<dim3(NT_OUT, MT), 256, 0, stream>>>(
                GARG(shb, Bb, out, nullptr, nullptr, coeff, 4 + k, zeta, muP, OUT_, IN_));
            else gemm_bt<0, 0, 1, 0, 0, 1, 0><<<dim3(NT_OUT, MT), 256, 0, stream>>>(
                GARG(shb, Bf, out, nullptr, nullptr, coeff, 4 + k, zeta, muP, OUT_, IN_));
        } else {
            gemm_bt<2, 1, 1, 0, 0, 1, 0><<<dim3(NT_OUT, MT), 256, 0, stream>>>(
                GARG(x, Bf, out, nullptr, nullptr, coeff, 4 + k, zeta, muP, OUT_, IN_));
        }
    }

    if (bf) {
        if (cw) gemm_bt<0, 0, 0, 5, 0, 1, 1><<<dim3(NT_OUT, MT), 256, 0, stream>>>(
            GARG(hb, calb, out, nullptr, cal_b, nullptr, 0, theta, muP, OUT_, IN_));
        else gemm_bt<0, 0, 1, 5, 0, 1, 1><<<dim3(NT_OUT, MT), 256, 0, stream>>>(
            GARG(hb, cal_w, out, nullptr, cal_b, nullptr, 0, theta, muP, OUT_, IN_));
    } else {
        gemm_bt<2, 0, 1, 5, 0, 1, 1><<<dim3(NT_OUT, MT), 256, 0, stream>>>(
            GARG(x, cal_w, out, nullptr, cal_b, nullptr, 0, theta, muP, OUT_, IN_));
    }

    for (int r0 = 0; r0 < B_; r0 += CH) {
        const int MTC = CH / 128;
        const unsigned short* xbC = bf ? xb + (size_t)r0 * IN_ : nullptr;
        const float* xC = x + (size_t)r0 * IN_;
        float* outC = out + (size_t)r0 * OUT_;
        const float* coeffC = coeff + (size_t)r0 * 8;
        for (int j = 0; j < 4; ++j) {
            dim3 gu(E[j] / 128, MTC);
            if (j == 0)
                LX(1, 1, 0, 0, gu, xbC, xC, upb[0], up_w[0], nullptr, U, nullptr, (const float*)nullptr, 0,
                   (const float*)nullptr, muP, E[0], IN_);
            else if (j == 1)
                LX(2, 1, 0, 0, gu, xbC, xC, upb[1], up_w[1], nullptr, U, nullptr, (const float*)nullptr, 0,
                   (const float*)nullptr, muP, E[1], IN_);
            else if (j == 2)
                LX(3, 1, 0, 0, gu, xbC, xC, upb[2], up_w[2], nullptr, U, nullptr, (const float*)nullptr, 0,
                   (const float*)nullptr, muP, E[2], IN_);
            else
                LX(4, 1, 0, 0, gu, xbC, xC, upb[3], up_w[3], nullptr, U, nullptr, (const float*)nullptr, 0,
                   (const float*)nullptr, muP, E[3], IN_);
            LD(0, 0, 1, 0, dim3(NT_OUT, MTC), U, downb[j], down_w[j], outC, nullptr, nullptr,
               coeffC, j, (const float*)nullptr, OUT_, E[j]);
        }
        LX(1, 1, 0, 0, dim3(4, MTC), xbC, xC, rg1b, rg_w1, nullptr, T, nullptr, (const float*)nullptr, 0,
           (const float*)nullptr, muP, 512, IN_);
        LD(5, 0, 1, 1, dim3(NT_OUT, MTC), T, rg2b, rg_w2, outC, nullptr, rg_b2, nullptr, 0, lam, OUT_, 512);
    }
#undef LX
#undef LD
#undef GARG
}

// Round 12
// 1972.715 us; speedup vs baseline: 1.1650x; 1.1650x over previous
//
#include <hip/hip_runtime.h>
#include <hip/hip_bf16.h>
#include <cstdint>
#include <cstddef>

#define DEVI __device__ __forceinline__

typedef short bf16x8 __attribute__((ext_vector_type(8)));
typedef float f32x4 __attribute__((ext_vector_type(4)));

static constexpr int B_ = 8192;
static constexpr int IN_ = 2048;
static constexpr int OUT_ = 1000;

DEVI float bf2f(unsigned short u) { return __uint_as_float(((unsigned int)u) << 16); }
DEVI unsigned short f2bf(float f) {
    unsigned int x = __float_as_uint(f);
    unsigned int r = x + 0x7FFFu + ((x >> 16) & 1u);
    return (unsigned short)(r >> 16);
}

DEVI void gload16(const unsigned short* g, unsigned short* l) {
    __builtin_amdgcn_global_load_lds((const __attribute__((address_space(1))) void*)g,
                                     (__attribute__((address_space(3))) void*)l, 16, 0, 0);
}

// XCD row-chunk swizzle (proven R3->R4): each XCD owns contiguous row-tiles.
DEVI void xcd_swizzle(int& bx, int& by) {
    const int NX = gridDim.x, NY = gridDim.y;
    if ((NY & 7) == 0) {
        const int NYc = NY >> 3;
        const int d = by * NX + bx;
        const int xcd = d & 7, idx = d >> 3;
        by = xcd * NYc + (idx % NYc);
        bx = idx / NYc;
    }
}

// fast tanh via hw exp: tanh(x) = 1 - 2/(e^{2x}+1), clamped
DEVI float fast_tanh(float x) {
    float xc = fminf(fmaxf(x, -10.f), 10.f);
    float e = __expf(2.f * xc);
    return 1.f - 2.f / (e + 1.f);
}

// ACT: 0=none 1=silu 2=gelu(exact) 3=mish 4=relu 5=tanh
template <int ACT> DEVI float apply_act(float v) {
    if constexpr (ACT == 1) return v / (1.f + __expf(-v));
    else if constexpr (ACT == 2) return 0.5f * v * (1.f + erff(v * 0.70710678118654752f));
    else if constexpr (ACT == 3) {
        float p = __expf(fminf(v, 20.f));
        float sp = (v > 20.f) ? v : __logf(1.f + p);
        return v * fast_tanh(sp);
    } else if constexpr (ACT == 4) return fmaxf(v, 0.f);
    else if constexpr (ACT == 5) return fast_tanh(v);
    else return v;
}

// ---------------- fp32 -> bf16 conversion ----------------
__global__ __launch_bounds__(256) void cvt_kernel(const float* __restrict__ in,
                                                  unsigned short* __restrict__ out, int n4) {
    int stride = gridDim.x * blockDim.x;
    for (int i = blockIdx.x * blockDim.x + threadIdx.x; i < n4; i += stride) {
        float4 v = ((const float4*)in)[i];
        ushort4 o;
        o.x = f2bf(v.x); o.y = f2bf(v.y); o.z = f2bf(v.z); o.w = f2bf(v.w);
        ((ushort4*)out)[i] = o;
    }
}

// dom_experts_w [4*1000][2048] f32 -> padded stacked [4*1024][2048] bf16 (pad rows zero)
__global__ __launch_bounds__(256) void cvt_dom_kernel(const float* __restrict__ in,
                                                      unsigned short* __restrict__ out) {
    const int total = 4096 * (IN_ / 4);
    int stride = gridDim.x * blockDim.x;
    for (int i = blockIdx.x * blockDim.x + threadIdx.x; i < total; i += stride) {
        int orow = i >> 9;
        int oc4 = i & 511;
        int s = orow >> 10, r = orow & 1023;
        ushort4 o = {0, 0, 0, 0};
        if (r < 1000) {
            float4 v = ((const float4*)(in + ((size_t)(s * 1000 + r)) * IN_))[oc4];
            o.x = f2bf(v.x); o.y = f2bf(v.y); o.z = f2bf(v.z); o.w = f2bf(v.w);
        }
        ((ushort4*)out)[i] = o;
    }
}

// ---------------- per-row LN stats (+ optional bf16 materialization) ----------------
__global__ __launch_bounds__(256) void stats_kernel(const float* __restrict__ x,
                                                    const float* __restrict__ g,
                                                    const float* __restrict__ bta,
                                                    float* __restrict__ mu,
                                                    float* __restrict__ rstd,
                                                    unsigned short* __restrict__ xb,
                                                    unsigned short* __restrict__ hb,
                                                    unsigned short* __restrict__ shb,
                                                    const int wX, const int wH, const int wS) {
    const int r = blockIdx.x;
    const int t = threadIdx.x;
    const float* xr = x + (size_t)r * IN_;
    float v[8];
    float s = 0.f, q = 0.f;
#pragma unroll
    for (int i = 0; i < 8; ++i) {
        v[i] = xr[t + i * 256];
        s += v[i];
        q += v[i] * v[i];
    }
#pragma unroll
    for (int off = 32; off > 0; off >>= 1) {
        s += __shfl_down(s, off);
        q += __shfl_down(q, off);
    }
    __shared__ float ss[4], qq[4];
    if ((t & 63) == 0) { ss[t >> 6] = s; qq[t >> 6] = q; }
    __syncthreads();
    s = ss[0] + ss[1] + ss[2] + ss[3];
    q = qq[0] + qq[1] + qq[2] + qq[3];
    const float mean = s * (1.f / IN_);
    const float var = q * (1.f / IN_) - mean * mean;
    const float rs = rsqrtf(var + 1e-5f);
    if (t == 0) { mu[r] = mean; rstd[r] = rs; }
#pragma unroll
    for (int i = 0; i < 8; ++i) {
        int c = t + i * 256;
        if (wX) xb[(size_t)r * IN_ + c] = f2bf(v[i]);
        if (wH | wS) {
            float h = (v[i] - mean) * rs * g[c] + bta[c];
            if (wH) hb[(size_t)r * IN_ + c] = f2bf(h);
            if (wS) shb[(size_t)r * IN_ + c] = f2bf(h / (1.f + __expf(-h)));
        }
    }
}

// ---------------- routers ----------------
__global__ __launch_bounds__(256) void router_kernel(
    const float* __restrict__ x, const float* __restrict__ mu, const float* __restrict__ rstd,
    const float* __restrict__ g, const float* __restrict__ bta,
    const float* __restrict__ rw0, const float* __restrict__ rb0,
    const float* __restrict__ rw1, const float* __restrict__ rb1,
    const float* __restrict__ rw2, const float* __restrict__ rb2,
    const float* __restrict__ rw3, const float* __restrict__ rb3,
    const float* __restrict__ scales, const float* __restrict__ domw,
    const float* __restrict__ domb, float* __restrict__ coeff) {
    const int r = blockIdx.x;
    const int t = threadIdx.x;
    __shared__ float xs[IN_];
    __shared__ float hs[IN_];
    __shared__ float dots[18];
    const float m = mu[r], rs = rstd[r];
#pragma unroll
    for (int i = 0; i < 8; ++i) {
        int c = t + i * 256;
        float xv = x[(size_t)r * IN_ + c];
        xs[c] = xv;
        hs[c] = (xv - m) * rs * g[c] + bta[c];
    }
    __syncthreads();
    const int w = t >> 6, l = t & 63;
    const float* wp[5] = {rw0, rw1, rw2, rw3, domw};
    for (int d = w; d < 18; d += 4) {
        int gidx, row;
        if (d < 2) { gidx = 0; row = d; }
        else if (d < 5) { gidx = 1; row = d - 2; }
        else if (d < 9) { gidx = 2; row = d - 5; }
        else if (d < 14) { gidx = 3; row = d - 9; }
        else { gidx = 4; row = d - 14; }
        const float* wt = wp[gidx] + (size_t)row * IN_;
        const float* src = (gidx == 4) ? hs : xs;
        float p = 0.f;
        for (int i = l; i < IN_; i += 64) p += src[i] * wt[i];
#pragma unroll
        for (int off = 32; off > 0; off >>= 1) p += __shfl_down(p, off);
        if (l == 0) dots[d] = p;
    }
    __syncthreads();
    if (t == 0) {
        const float* rbs[4] = {rb0, rb1, rb2, rb3};
        float c[4] = {0.f, 0.f, 0.f, 0.f};
        int off = 0;
        for (int i = 0; i < 4; ++i) {
            int n = i + 2;
            float lg[5], mx = -1e30f;
            for (int j = 0; j < n; ++j) { lg[j] = dots[off + j] + rbs[i][j]; mx = fmaxf(mx, lg[j]); }
            float den = 0.f;
            for (int j = 0; j < n; ++j) { lg[j] = expf(lg[j] - mx); den += lg[j]; }
            float inv = 1.f / den;
            float sci = scales[i];
            for (int j = 0; j <= i; ++j) c[j] += sci * lg[j] * inv;
            off += n;
        }
        float dl[4], mx = -1e30f;
        for (int k = 0; k < 4; ++k) { dl[k] = dots[14 + k] + domb[k]; mx = fmaxf(mx, dl[k]); }
        float den = 0.f;
        for (int k = 0; k < 4; ++k) { dl[k] = expf(dl[k] - mx); den += dl[k]; }
        float inv = 1.f / den;
        for (int j = 0; j < 4; ++j) coeff[(size_t)r * 8 + j] = c[j];
        for (int k = 0; k < 4; ++k) coeff[(size_t)r * 8 + 4 + k] = dl[k] * inv;
    }
}

// ---------- dom reduce: out[r][c] += zeta * sum_s coeff[r][4+s] * U[r][s*1024+c] ----------
__global__ __launch_bounds__(256) void dom_reduce(
    const unsigned short* __restrict__ U, const float* __restrict__ coeff,
    float* __restrict__ out, const float* __restrict__ zetap) {
    const float zeta = zetap[0];
    const int nGroups = B_ * (OUT_ / 8);  // 8192 * 125
    const int stride = gridDim.x * blockDim.x;
    for (int i = blockIdx.x * blockDim.x + threadIdx.x; i < nGroups; i += stride) {
        const int r = i / 125;
        const int c8 = (i - r * 125) * 8;
        const float w0 = zeta * coeff[(size_t)r * 8 + 4];
        const float w1 = zeta * coeff[(size_t)r * 8 + 5];
        const float w2 = zeta * coeff[(size_t)r * 8 + 6];
        const float w3 = zeta * coeff[(size_t)r * 8 + 7];
        const unsigned short* ur = U + (size_t)r * 4096 + c8;
        bf16x8 p0 = *(const bf16x8*)(ur);
        bf16x8 p1 = *(const bf16x8*)(ur + 1024);
        bf16x8 p2 = *(const bf16x8*)(ur + 2048);
        bf16x8 p3 = *(const bf16x8*)(ur + 3072);
        float* orow = out + (size_t)r * OUT_ + c8;
#pragma unroll
        for (int j = 0; j < 8; ++j) {
            orow[j] += w0 * bf2f((unsigned short)p0[j]) + w1 * bf2f((unsigned short)p1[j]) +
                       w2 * bf2f((unsigned short)p2[j]) + w3 * bf2f((unsigned short)p3[j]);
        }
    }
}

// ============ 256x256 4-sub-phase bf16 GEMM — counted-vmcnt variant ============
// Change vs R10 (verified): next-tile stage issued BEFORE the top wait; wait is
// vmcnt(8) (drains exactly tile t's 8 loads, leaves t+1's in flight); new end-of-
// iteration barrier guarantees all reads of buf t retire before t+2 stages into it.
template <int ACT>
__global__ __launch_bounds__(512, 2) void gemm8p(
    const unsigned short* __restrict__ A, const unsigned short* __restrict__ Bw,
    unsigned short* __restrict__ outB, const int N, const int K) {
    extern __shared__ unsigned short lds[];
    const int t = threadIdx.x;
    const int l = t & 63, w = t >> 6;
    const int wr = w >> 2, wc = w & 3;
    int bx = blockIdx.x, by = blockIdx.y;
    xcd_swizzle(bx, by);
    const int rowBase = by * 256, colBase = bx * 256;

    const int lr = l >> 3;
    const int lcs = (((l & 7) ^ lr) << 3);
    const unsigned short* aSrc[4];
    const unsigned short* bSrc[4];
    int aDst[4], bDst[4];
#pragma unroll
    for (int j = 0; j < 4; ++j) {
        const int h = j >> 1, ci = w * 2 + (j & 1);
        aSrc[j] = A + (size_t)(rowBase + h * 128 + ci * 8 + lr) * K + lcs;
        bSrc[j] = Bw + (size_t)(colBase + h * 128 + ci * 8 + lr) * K + lcs;
        aDst[j] = h * 8192 + ci * 512;
        bDst[j] = 16384 + h * 8192 + ci * 512;
    }

    const int fr = l & 15, fg = l >> 4;
    const int kx0 = ((fg ^ (fr & 7)) << 3);
    const int kx1 = (((4 + fg) ^ (fr & 7)) << 3);
    const int aRow = (wr * 128 + fr) * 64;
    const int bRow = 16384 + (wc * 64 + fr) * 64;

    f32x4 acc[8][4];
#pragma unroll
    for (int m = 0; m < 8; ++m)
#pragma unroll
        for (int n = 0; n < 4; ++n) acc[m][n] = (f32x4){0.f, 0.f, 0.f, 0.f};

    const int nt = K >> 6;

#pragma unroll
    for (int j = 0; j < 4; ++j) gload16(aSrc[j], &lds[aDst[j]]);
#pragma unroll
    for (int j = 0; j < 4; ++j) gload16(bSrc[j], &lds[bDst[j]]);

    bf16x8 aF[4][2], bF[2][2];

#define LOAD_A(mh)                                                                         \
    _Pragma("unroll") for (int m = 0; m < 4; ++m) {                                        \
        aF[m][0] = *(const bf16x8*)&lds[bo + aRow + ((mh)*64 + m * 16) * 64 + kx0];        \
        aF[m][1] = *(const bf16x8*)&lds[bo + aRow + ((mh)*64 + m * 16) * 64 + kx1];        \
    }
#define LOAD_B(nh)                                                                         \
    _Pragma("unroll") for (int n = 0; n < 2; ++n) {                                        \
        bF[n][0] = *(const bf16x8*)&lds[bo + bRow + ((nh)*32 + n * 16) * 64 + kx0];        \
        bF[n][1] = *(const bf16x8*)&lds[bo + bRow + ((nh)*32 + n * 16) * 64 + kx1];        \
    }
#define MFMA_PHASE(mh, nh)                                                                 \
    __builtin_amdgcn_s_setprio(1);                                                         \
    _Pragma("unroll") for (int m = 0; m < 4; ++m)                                          \
        _Pragma("unroll") for (int n = 0; n < 2; ++n) {                                    \
            acc[(mh)*4 + m][(nh)*2 + n] = __builtin_amdgcn_mfma_f32_16x16x32_bf16(         \
                aF[m][0], bF[n][0], acc[(mh)*4 + m][(nh)*2 + n], 0, 0, 0);                 \
            acc[(mh)*4 + m][(nh)*2 + n] = __builtin_amdgcn_mfma_f32_16x16x32_bf16(         \
                aF[m][1], bF[n][1], acc[(mh)*4 + m][(nh)*2 + n], 0, 0, 0);                 \
        }                                                                                  \
    __builtin_amdgcn_s_setprio(0);

    for (int ti = 0; ti < nt; ++ti) {
        const int bo = (ti & 1) << 15;
        const int so = bo ^ 32768;
        const int ko = (ti + 1) << 6;
        const bool pre = (ti + 1 < nt);
        // ---- issue next-tile stage, then counted wait on THIS tile's loads ----
        if (pre) {
#pragma unroll
            for (int j = 0; j < 4; ++j) gload16(aSrc[j] + ko, &lds[so + aDst[j]]);
#pragma unroll
            for (int j = 0; j < 4; ++j) gload16(bSrc[j] + ko, &lds[so + bDst[j]]);
            asm volatile("s_waitcnt vmcnt(8)" ::: "memory");
        } else {
            asm volatile("s_waitcnt vmcnt(0)" ::: "memory");
        }
        asm volatile("s_barrier" ::: "memory");   // tile ti resident for ALL waves
        LOAD_A(0)
        LOAD_B(0)
        MFMA_PHASE(0, 0)
        asm volatile("s_barrier" ::: "memory");
        LOAD_A(1)
        MFMA_PHASE(1, 0)
        asm volatile("s_barrier" ::: "memory");
        LOAD_B(1)
        MFMA_PHASE(1, 1)
        asm volatile("s_barrier" ::: "memory");
        LOAD_A(0)
        MFMA_PHASE(0, 1)
        asm volatile("s_barrier" ::: "memory");   // all reads of bo retired before next
    }
#undef LOAD_A
#undef LOAD_B
#undef MFMA_PHASE

#pragma unroll
    for (int m = 0; m < 8; ++m) {
        const int grow0 = rowBase + wr * 128 + m * 16 + fg * 4;
#pragma unroll
        for (int n = 0; n < 4; ++n) {
            const int gcol = colBase + wc * 64 + n * 16 + fr;
#pragma unroll
            for (int j = 0; j < 4; ++j) {
                float v = apply_act<ACT>(acc[m][n][j]);
                outB[(size_t)(grow0 + j) * N + gcol] = f2bf(v);
            }
        }
    }
}

// ============ 128x128 BK=64 GEMM with gemm8p swizzle (R10-verified) ============
// MODE: 0 = write f32 (+bias), 1 = accumulate f32, 2 = write bf16.
template <int ACT, int MODE, int BIASF>
__global__ __launch_bounds__(256) void gemm_bk64(
    const unsigned short* __restrict__ A, const unsigned short* __restrict__ Bw,
    float* __restrict__ outF, unsigned short* __restrict__ outB,
    const float* __restrict__ bias, const float* __restrict__ coeff, const int cidx,
    const float* __restrict__ scalarp, const int N, const int K) {
    __shared__ unsigned short Asm[2][8192];
    __shared__ unsigned short Bsm[2][8192];
    const int t = threadIdx.x;
    const int l = t & 63;
    const int w = t >> 6;
    const int wr = w >> 1, wc = w & 1;
    int bx = blockIdx.x, by = blockIdx.y;
    xcd_swizzle(bx, by);
    const int rowBase = by * 128;
    const int colBase = bx * 128;

    const int lr = l >> 3;
    const int lcs = (((l & 7) ^ lr) << 3);
    const unsigned short* aS[4];
    const unsigned short* bS[4];
    int dst[4];
#pragma unroll
    for (int i = 0; i < 4; ++i) {
        const int r0 = w * 32 + i * 8;
        const int ar = rowBase + r0 + lr;
        int br = colBase + r0 + lr; if (br >= N) br = N - 1;
        aS[i] = A + (size_t)ar * K + lcs;
        bS[i] = Bw + (size_t)br * K + lcs;
        dst[i] = r0 * 64;
    }

    f32x4 acc[4][4];
#pragma unroll
    for (int m = 0; m < 4; ++m)
#pragma unroll
        for (int n = 0; n < 4; ++n) acc[m][n] = (f32x4){0.f, 0.f, 0.f, 0.f};

    const int nK = K >> 6;

    auto stage = [&](int buf, int kt) {
        const int ko = kt << 6;
#pragma unroll
        for (int i = 0; i < 4; ++i) gload16(aS[i] + ko, &Asm[buf][dst[i]]);
#pragma unroll
        for (int i = 0; i < 4; ++i) gload16(bS[i] + ko, &Bsm[buf][dst[i]]);
    };

    stage(0, 0);
    __syncthreads();

    const int fr = l & 15;
    const int fg = l >> 4;
    const int kx0 = ((fg ^ (fr & 7)) << 3);
    const int kx1 = (((4 + fg) ^ (fr & 7)) << 3);

    int buf = 0;
    for (int kt = 0; kt < nK; ++kt) {
        if (kt + 1 < nK) stage(buf ^ 1, kt + 1);
        bf16x8 af[4][2], bfr[4][2];
#pragma unroll
        for (int m = 0; m < 4; ++m) {
            const int ar = (wr * 64 + m * 16 + fr) * 64;
            af[m][0] = *(const bf16x8*)&Asm[buf][ar + kx0];
            af[m][1] = *(const bf16x8*)&Asm[buf][ar + kx1];
        }
#pragma unroll
        for (int n = 0; n < 4; ++n) {
            const int br = (wc * 64 + n * 16 + fr) * 64;
            bfr[n][0] = *(const bf16x8*)&Bsm[buf][br + kx0];
            bfr[n][1] = *(const bf16x8*)&Bsm[buf][br + kx1];
        }
#pragma unroll
        for (int m = 0; m < 4; ++m)
#pragma unroll
            for (int n = 0; n < 4; ++n) {
                acc[m][n] = __builtin_amdgcn_mfma_f32_16x16x32_bf16(af[m][0], bfr[n][0], acc[m][n], 0, 0, 0);
                acc[m][n] = __builtin_amdgcn_mfma_f32_16x16x32_bf16(af[m][1], bfr[n][1], acc[m][n], 0, 0, 0);
            }
        __syncthreads();
        buf ^= 1;
    }

    const float scal = scalarp ? scalarp[0] : 1.0f;
#pragma unroll
    for (int m = 0; m < 4; ++m) {
        const int grow0 = rowBase + wr * 64 + m * 16 + fg * 4;
#pragma unroll
        for (int n = 0; n < 4; ++n) {
            const int gcol = colBase + wc * 64 + n * 16 + fr;
            if (gcol < N) {
                float bv = BIASF ? bias[gcol] : 0.f;
#pragma unroll
                for (int j = 0; j < 4; ++j) {
                    const int grow = grow0 + j;
                    float v = acc[m][n][j] + bv;
                    v = apply_act<ACT>(v);
                    float alpha = scal;
                    if (coeff) alpha *= coeff[(size_t)grow * 8 + cidx];
                    v *= alpha;
                    const size_t o = (size_t)grow * N + gcol;
                    if constexpr (MODE == 2) outB[o] = f2bf(v);
                    else if constexpr (MODE == 1) outF[o] += v;
                    else outF[o] = v;
                }
            }
        }
    }
}

// ============ bf16 MFMA GEMM, BK=32 128x128 (large-grid dom stage 1) ============
template <int ACT, int MODE, int BIASF>
__global__ __launch_bounds__(256) void gemm_lds(
    const unsigned short* __restrict__ A, const unsigned short* __restrict__ Bw,
    float* __restrict__ outF, unsigned short* __restrict__ outB,
    const float* __restrict__ bias, const float* __restrict__ coeff, const int cidx,
    const float* __restrict__ scalarp, const int N, const int K) {
    __shared__ unsigned short Asm[2][4096];
    __shared__ unsigned short Bsm[2][4096];
    const int t = threadIdx.x;
    const int l = t & 63;
    const int w = t >> 6;
    const int wr = w >> 1, wc = w & 1;
    int bx = blockIdx.x, by = blockIdx.y;
    xcd_swizzle(bx, by);
    const int rowBase = by * 128;
    const int colBase = bx * 128;

    const int lr = l >> 2;
    const int lk = (l & 3) << 3;
    const int ar0 = rowBase + w * 32 + lr;
    const int ar1 = ar0 + 16;
    int br0 = colBase + w * 32 + lr;      if (br0 >= N) br0 = N - 1;
    int br1 = colBase + w * 32 + 16 + lr; if (br1 >= N) br1 = N - 1;
    const unsigned short* pA0 = A + (size_t)ar0 * K + lk;
    const unsigned short* pA1 = A + (size_t)ar1 * K + lk;
    const unsigned short* pB0 = Bw + (size_t)br0 * K + lk;
    const unsigned short* pB1 = Bw + (size_t)br1 * K + lk;
    const int ldsA0 = (w * 32) * 32;
    const int ldsA1 = (w * 32 + 16) * 32;

    f32x4 acc[4][4];
#pragma unroll
    for (int m = 0; m < 4; ++m)
#pragma unroll
        for (int n = 0; n < 4; ++n) acc[m][n] = (f32x4){0.f, 0.f, 0.f, 0.f};

    const int nK = K >> 5;

    auto stage = [&](int buf, int kt) {
        const int ko = kt << 5;
        gload16(pA0 + ko, &Asm[buf][ldsA0]);
        gload16(pA1 + ko, &Asm[buf][ldsA1]);
        gload16(pB0 + ko, &Bsm[buf][ldsA0]);
        gload16(pB1 + ko, &Bsm[buf][ldsA1]);
    };

    stage(0, 0);
    __syncthreads();

    const int fr = l & 15;
    const int fg = l >> 4;
    const int aoff = (wr * 64 + fr) * 32 + fg * 8;
    const int boff = (wc * 64 + fr) * 32 + fg * 8;

    int buf = 0;
    for (int kt = 0; kt < nK; ++kt) {
        if (kt + 1 < nK) stage(buf ^ 1, kt + 1);
        bf16x8 af[4], bfr[4];
#pragma unroll
        for (int m = 0; m < 4; ++m) af[m] = *(const bf16x8*)&Asm[buf][aoff + m * 512];
#pragma unroll
        for (int n = 0; n < 4; ++n) bfr[n] = *(const bf16x8*)&Bsm[buf][boff + n * 512];
#pragma unroll
        for (int m = 0; m < 4; ++m)
#pragma unroll
            for (int n = 0; n < 4; ++n)
                acc[m][n] = __builtin_amdgcn_mfma_f32_16x16x32_bf16(af[m], bfr[n], acc[m][n], 0, 0, 0);
        __syncthreads();
        buf ^= 1;
    }

    const float scal = scalarp ? scalarp[0] : 1.0f;
#pragma unroll
    for (int m = 0; m < 4; ++m) {
        const int grow0 = rowBase + wr * 64 + m * 16 + fg * 4;
#pragma unroll
        for (int n = 0; n < 4; ++n) {
            const int gcol = colBase + wc * 64 + n * 16 + fr;
            if (gcol < N) {
                float bv = BIASF ? bias[gcol] : 0.f;
#pragma unroll
                for (int j = 0; j < 4; ++j) {
                    const int grow = grow0 + j;
                    float v = acc[m][n][j] + bv;
                    v = apply_act<ACT>(v);
                    float alpha = scal;
                    if (coeff) alpha *= coeff[(size_t)grow * 8 + cidx];
                    v *= alpha;
                    const size_t o = (size_t)grow * N + gcol;
                    if constexpr (MODE == 2) outB[o] = f2bf(v);
                    else if constexpr (MODE == 1) outF[o] += v;
                    else outF[o] = v;
                }
            }
        }
    }
}

// ---------------- generic (fallback-tier) GEMM: reg-staged, fp32-capable sources ----------------
template <int ASRC, int ASIL, int BSRC, int ACT, int OUTBF, int ACCUM, int BIASF>
__global__ __launch_bounds__(256) void gemm_bt(
    const void* __restrict__ Ap, const void* __restrict__ Bp,
    float* __restrict__ outF, unsigned short* __restrict__ outB,
    const float* __restrict__ bias, const float* __restrict__ coeff, const int cidx,
    const float* __restrict__ scalarp,
    const float* __restrict__ muP, const float* __restrict__ rsP,
    const float* __restrict__ lng, const float* __restrict__ lnb,
    const int N, const int K) {
    __shared__ unsigned short Asm[2][4096];
    __shared__ unsigned short Bsm[2][4096];
    const int t = threadIdx.x;
    const int l = t & 63;
    const int w = t >> 6;
    const int wr = w >> 1, wc = w & 1;
    int bx = blockIdx.x, by = blockIdx.y;
    xcd_swizzle(bx, by);
    const int rowBase = by * 128;
    const int colBase = bx * 128;

    const int srow = t >> 2;
    const int skol = (t & 3) << 3;
    const int arow0 = rowBase + srow;
    const int arow1 = arow0 + 64;
    int br0 = colBase + srow;        if (br0 >= N) br0 = N - 1;
    int br1 = colBase + srow + 64;   if (br1 >= N) br1 = N - 1;

    float mu0 = 0.f, rs0 = 1.f, mu1 = 0.f, rs1 = 1.f;
    if constexpr (ASRC == 2) {
        mu0 = muP[arow0]; rs0 = rsP[arow0];
        mu1 = muP[arow1]; rs1 = rsP[arow1];
    }

    auto ldA = [&](int row, float mu_, float rs_, int k0) -> bf16x8 {
        if constexpr (ASRC == 0) {
            bf16x8 v = *(const bf16x8*)((const unsigned short*)Ap + (size_t)row * K + k0);
            if constexpr (ASIL) {
                bf16x8 r;
#pragma unroll
                for (int i = 0; i < 8; ++i) {
                    float f = bf2f((unsigned short)v[i]);
                    r[i] = (short)f2bf(f / (1.f + __expf(-f)));
                }
                return r;
            }
            return v;
        } else {
            const float* f = (const float*)Ap + (size_t)row * K + k0;
            float4 v0 = *(const float4*)f;
            float4 v1 = *(const float4*)(f + 4);
            float vv[8] = {v0.x, v0.y, v0.z, v0.w, v1.x, v1.y, v1.z, v1.w};
            if constexpr (ASRC == 2) {
                float4 g0 = *(const float4*)(lng + k0), g1 = *(const float4*)(lng + k0 + 4);
                float4 b0 = *(const float4*)(lnb + k0), b1 = *(const float4*)(lnb + k0 + 4);
                float gg[8] = {g0.x, g0.y, g0.z, g0.w, g1.x, g1.y, g1.z, g1.w};
                float bb[8] = {b0.x, b0.y, b0.z, b0.w, b1.x, b1.y, b1.z, b1.w};
#pragma unroll
                for (int i = 0; i < 8; ++i) vv[i] = (vv[i] - mu_) * rs_ * gg[i] + bb[i];
            }
            if constexpr (ASIL) {
#pragma unroll
                for (int i = 0; i < 8; ++i) vv[i] = vv[i] / (1.f + __expf(-vv[i]));
            }
            bf16x8 r;
#pragma unroll
            for (int i = 0; i < 8; ++i) r[i] = (short)f2bf(vv[i]);
            return r;
        }
    };
    auto ldB = [&](int row, int k0) -> bf16x8 {
        if constexpr (BSRC == 0) {
            return *(const bf16x8*)((const unsigned short*)Bp + (size_t)row * K + k0);
        } else {
            const float* f = (const float*)Bp + (size_t)row * K + k0;
            float4 v0 = *(const float4*)f;
            float4 v1 = *(const float4*)(f + 4);
            float vv[8] = {v0.x, v0.y, v0.z, v0.w, v1.x, v1.y, v1.z, v1.w};
            bf16x8 r;
#pragma unroll
            for (int i = 0; i < 8; ++i) r[i] = (short)f2bf(vv[i]);
            return r;
        }
    };

    const int wo = t * 8;

    f32x4 acc[4][4];
#pragma unroll
    for (int m = 0; m < 4; ++m)
#pragma unroll
        for (int n = 0; n < 4; ++n) acc[m][n] = (f32x4){0.f, 0.f, 0.f, 0.f};

    const int nK = K >> 5;

    bf16x8 a0 = ldA(arow0, mu0, rs0, skol);
    bf16x8 a1 = ldA(arow1, mu1, rs1, skol);
    bf16x8 b0 = ldB(br0, skol);
    bf16x8 b1 = ldB(br1, skol);
    *(bf16x8*)&Asm[0][wo] = a0; *(bf16x8*)&Asm[0][wo + 2048] = a1;
    *(bf16x8*)&Bsm[0][wo] = b0; *(bf16x8*)&Bsm[0][wo + 2048] = b1;
    __syncthreads();

    const int fr = l & 15;
    const int fg = l >> 4;
    const int aoff = (wr * 64 + fr) * 32 + fg * 8;
    const int boff = (wc * 64 + fr) * 32 + fg * 8;

    for (int kt = 0; kt < nK; ++kt) {
        const int cur = kt & 1;
        if (kt + 1 < nK) {
            const int ko = ((kt + 1) << 5) + skol;
            a0 = ldA(arow0, mu0, rs0, ko);
            a1 = ldA(arow1, mu1, rs1, ko);
            b0 = ldB(br0, ko);
            b1 = ldB(br1, ko);
        }
        bf16x8 af[4], bfr[4];
#pragma unroll
        for (int m = 0; m < 4; ++m) af[m] = *(const bf16x8*)&Asm[cur][aoff + m * 512];
#pragma unroll
        for (int n = 0; n < 4; ++n) bfr[n] = *(const bf16x8*)&Bsm[cur][boff + n * 512];
#pragma unroll
        for (int m = 0; m < 4; ++m)
#pragma unroll
            for (int n = 0; n < 4; ++n)
                acc[m][n] = __builtin_amdgcn_mfma_f32_16x16x32_bf16(af[m], bfr[n], acc[m][n], 0, 0, 0);
        if (kt + 1 < nK) {
            __syncthreads();
            const int nxt = cur ^ 1;
            *(bf16x8*)&Asm[nxt][wo] = a0; *(bf16x8*)&Asm[nxt][wo + 2048] = a1;
            *(bf16x8*)&Bsm[nxt][wo] = b0; *(bf16x8*)&Bsm[nxt][wo + 2048] = b1;
            __syncthreads();
        }
    }

    const float scal = scalarp ? scalarp[0] : 1.0f;
#pragma unroll
    for (int m = 0; m < 4; ++m) {
        const int grow0 = rowBase + wr * 64 + m * 16 + fg * 4;
#pragma unroll
        for (int n = 0; n < 4; ++n) {
            const int gcol = colBase + wc * 64 + n * 16 + fr;
            if (gcol < N) {
                float bv = BIASF ? bias[gcol] : 0.f;
#pragma unroll
                for (int j = 0; j < 4; ++j) {
                    const int grow = grow0 + j;
                    float v = acc[m][n][j] + bv;
                    v = apply_act<ACT>(v);
                    float alpha = scal;
                    if (coeff) alpha *= coeff[(size_t)grow * 8 + cidx];
                    v *= alpha;
                    const size_t o = (size_t)grow * N + gcol;
                    if (OUTBF) outB[o] = f2bf(v);
                    else if (ACCUM) outF[o] += v;
                    else outF[o] = v;
                }
            }
        }
    }
}

static inline void cvt(const float* in, unsigned short* out, size_t n, hipStream_t s) {
    int n4 = (int)(n >> 2);
    int blocks = (n4 + 255) / 256;
    if (blocks > 4096) blocks = 4096;
    cvt_kernel<<<blocks, 256, 0, s>>>(in, out, n4);
}

extern "C" void kernel_launch(void* const* d_in, const int* in_sizes, int n_in,
                              void* d_out, int out_size, void* d_ws, size_t ws_size,
                              hipStream_t stream) {
    (void)in_sizes; (void)n_in; (void)out_size;
    const float* x = (const float*)d_in[0];
    const float* W = (const float*)d_in[1];
    const float* bvec = (const float*)d_in[2];
    const float* up_w[4] = {(const float*)d_in[3], (const float*)d_in[7], (const float*)d_in[11], (const float*)d_in[15]};
    const float* down_w[4] = {(const float*)d_in[4], (const float*)d_in[8], (const float*)d_in[12], (const float*)d_in[16]};
    const float* r_w[4] = {(const float*)d_in[5], (const float*)d_in[9], (const float*)d_in[13], (const float*)d_in[17]};
    const float* r_b[4] = {(const float*)d_in[6], (const float*)d_in[10], (const float*)d_in[14], (const float*)d_in[18]};
    const float* scales = (const float*)d_in[19];
    const float* ln_g = (const float*)d_in[20];
    const float* ln_b = (const float*)d_in[21];
    const float* dom_rw = (const float*)d_in[22];
    const float* dom_rb = (const float*)d_in[23];
    const float* dom_ew = (const float*)d_in[24];
    const float* cal_w = (const float*)d_in[25];
    const float* cal_b = (const float*)d_in[26];
    const float* rg_w1 = (const float*)d_in[27];
    const float* rg_w2 = (const float*)d_in[28];
    const float* rg_b2 = (const float*)d_in[29];
    const float* zeta = (const float*)d_in[30];
    const float* theta = (const float*)d_in[31];
    const float* lam = (const float*)d_in[32];
    float* out = (float*)d_out;

    const int E[4] = {2048, 4096, 6144, 8192};
    auto al = [](size_t v) { return (v + 255) & ~(size_t)255; };

    size_t fastNeed = al((size_t)B_ * 8 * 4) + 2 * al((size_t)B_ * 4) +
                      2 * al((size_t)B_ * IN_ * 2) +
                      al((size_t)OUT_ * IN_ * 2) +
                      al((size_t)4096 * IN_ * 2) +
                      al((size_t)OUT_ * IN_ * 2) +
                      al((size_t)512 * IN_ * 2) + al((size_t)OUT_ * 512 * 2) +
                      al((size_t)B_ * 8192 * 2) + al((size_t)B_ * 512 * 2);
    for (int j = 0; j < 4; ++j)
        fastNeed += al((size_t)E[j] * IN_ * 2) + al((size_t)OUT_ * E[j] * 2);

    char* p = (char*)d_ws;
    auto alloc = [&](size_t bytes) { char* r = p; p += (bytes + 255) & ~(size_t)255; return r; };

    const int NT_OUT = (OUT_ + 127) / 128;  // 8
    const int MT = B_ / 128;                // 64

    if (ws_size >= fastNeed) {
        // ================= FAST PATH (R10-verified structure; gemm8p counted-vmcnt) =================
        float* coeff = (float*)alloc((size_t)B_ * 8 * 4);
        float* muP = (float*)alloc((size_t)B_ * 4);
        float* rsP = (float*)alloc((size_t)B_ * 4);
        unsigned short* xb = (unsigned short*)alloc((size_t)B_ * IN_ * 2);
        unsigned short* shb = (unsigned short*)alloc((size_t)B_ * IN_ * 2);
        unsigned short* Wb = (unsigned short*)alloc((size_t)OUT_ * IN_ * 2);
        unsigned short* domN = (unsigned short*)alloc((size_t)4096 * IN_ * 2);
        unsigned short* calb = (unsigned short*)alloc((size_t)OUT_ * IN_ * 2);
        unsigned short* rg1b = (unsigned short*)alloc((size_t)512 * IN_ * 2);
        unsigned short* rg2b = (unsigned short*)alloc((size_t)OUT_ * 512 * 2);
        unsigned short* U = (unsigned short*)alloc((size_t)B_ * 8192 * 2);
        unsigned short* T = (unsigned short*)alloc((size_t)B_ * 512 * 2);
        unsigned short* upb[4];
        unsigned short* downb[4];
        for (int j = 0; j < 4; ++j) {
            upb[j] = (unsigned short*)alloc((size_t)E[j] * IN_ * 2);
            downb[j] = (unsigned short*)alloc((size_t)OUT_ * E[j] * 2);
        }
        unsigned short* hbU = U;  // h bf16 borrows U until dom-partial overwrites it

        hipFuncSetAttribute((const void*)gemm8p<1>, hipFuncAttributeMaxDynamicSharedMemorySize, 131072);
        hipFuncSetAttribute((const void*)gemm8p<2>, hipFuncAttributeMaxDynamicSharedMemorySize, 131072);
        hipFuncSetAttribute((const void*)gemm8p<3>, hipFuncAttributeMaxDynamicSharedMemorySize, 131072);
        hipFuncSetAttribute((const void*)gemm8p<4>, hipFuncAttributeMaxDynamicSharedMemorySize, 131072);

        // weight conversions
        cvt(W, Wb, (size_t)OUT_ * IN_, stream);
        cvt_dom_kernel<<<4096, 256, 0, stream>>>(dom_ew, domN);
        cvt(cal_w, calb, (size_t)OUT_ * IN_, stream);
        cvt(rg_w1, rg1b, (size_t)512 * IN_, stream);
        cvt(rg_w2, rg2b, (size_t)OUT_ * 512, stream);
        for (int j = 0; j < 4; ++j) {
            cvt(up_w[j], upb[j], (size_t)E[j] * IN_, stream);
            cvt(down_w[j], downb[j], (size_t)OUT_ * E[j], stream);
        }

        // stats (xb, h -> U scratch, silu(h)) + router coeffs
        stats_kernel<<<B_, 256, 0, stream>>>(x, ln_g, ln_b, muP, rsP, xb, hbU, shb, 1, 1, 1);
        router_kernel<<<B_, 256, 0, stream>>>(x, muP, rsP, ln_g, ln_b,
                                              r_w[0], r_b[0], r_w[1], r_b[1], r_w[2], r_b[2],
                                              r_w[3], r_b[3], scales, dom_rw, dom_rb, coeff);

        // base: out = x @ W^T + b (full write, clears poison)
        gemm_bk64<0, 0, 1><<<dim3(NT_OUT, MT), 256, 0, stream>>>(
            xb, Wb, out, nullptr, bvec, nullptr, 0, nullptr, OUT_, IN_);

        // calib: out += theta * tanh(h @ calib^T + calib_b)  (reads h from U, before dom clobbers)
        gemm_bk64<5, 1, 1><<<dim3(NT_OUT, MT), 256, 0, stream>>>(
            hbU, calb, out, nullptr, cal_b, nullptr, 0, theta, OUT_, IN_);

        // dom stage 1: partials U[8192][4096] = shb @ domN^T (bf16, 2048 blocks — keep BK32)
        gemm_lds<0, 2, 0><<<dim3(32, MT), 256, 0, stream>>>(
            shb, domN, nullptr, U, nullptr, nullptr, 0, nullptr, 4096, IN_);
        // dom stage 2: out += zeta * sum_s w_s[row] * U[row][s*1024+c]
        dom_reduce<<<2048, 256, 0, stream>>>(U, coeff, out, zeta);

        // branches: U = act_j(x @ up_j^T) via 256^2 counted-vmcnt kernel; downs accumulate (BK64)
        gemm8p<1><<<dim3(E[0] / 256, B_ / 256), 512, 131072, stream>>>(xb, upb[0], U, E[0], IN_);
        gemm_bk64<0, 1, 0><<<dim3(NT_OUT, MT), 256, 0, stream>>>(
            U, downb[0], out, nullptr, nullptr, coeff, 0, nullptr, OUT_, E[0]);
        gemm8p<2><<<dim3(E[1] / 256, B_ / 256), 512, 131072, stream>>>(xb, upb[1], U, E[1], IN_);
        gemm_bk64<0, 1, 0><<<dim3(NT_OUT, MT), 256, 0, stream>>>(
            U, downb[1], out, nullptr, nullptr, coeff, 1, nullptr, OUT_, E[1]);
        gemm8p<3><<<dim3(E[2] / 256, B_ / 256), 512, 131072, stream>>>(xb, upb[2], U, E[2], IN_);
        gemm_bk64<0, 1, 0><<<dim3(NT_OUT, MT), 256, 0, stream>>>(
            U, downb[2], out, nullptr, nullptr, coeff, 2, nullptr, OUT_, E[2]);
        gemm8p<4><<<dim3(E[3] / 256, B_ / 256), 512, 131072, stream>>>(xb, upb[3], U, E[3], IN_);
        gemm_bk64<0, 1, 0><<<dim3(NT_OUT, MT), 256, 0, stream>>>(
            U, downb[3], out, nullptr, nullptr, coeff, 3, nullptr, OUT_, E[3]);

        // reason: T = silu(x @ rg1^T); out += lambda * tanh(T @ rg2^T + rg_b2)
        gemm_bk64<1, 2, 0><<<dim3(4, MT), 256, 0, stream>>>(
            xb, rg1b, nullptr, T, nullptr, nullptr, 0, nullptr, 512, IN_);
        gemm_bk64<5, 1, 1><<<dim3(NT_OUT, MT), 256, 0, stream>>>(
            T, rg2b, out, nullptr, rg_b2, nullptr, 0, lam, OUT_, 512);
        return;
    }

    // ================= FALLBACK TIERS (verified R2 path) =================
    const size_t S_coeff = al((size_t)B_ * 8 * 4);
    const size_t S_mu = al((size_t)B_ * 4);
    const size_t S_act = al((size_t)B_ * IN_ * 2);
    size_t S_W = al((size_t)OUT_ * IN_ * 2) + al((size_t)4 * OUT_ * IN_ * 2) +
                 al((size_t)OUT_ * IN_ * 2) + al((size_t)512 * IN_ * 2) + al((size_t)OUT_ * 512 * 2);
    for (int j = 0; j < 4; ++j) S_W += al((size_t)E[j] * IN_ * 2) + al((size_t)OUT_ * E[j] * 2);

    auto needOf = [&](bool bfl, bool cwl, int ch) {
        size_t n = S_coeff + 2 * S_mu;
        if (bfl) n += 3 * S_act;
        if (cwl) n += S_W;
        n += al((size_t)ch * 8192 * 2) + al((size_t)ch * 512 * 2);
        return n;
    };
    bool bf = false, cw = false;
    int CH = 512;
    {
        const bool cb[7] = {true, true, true, true, true, true, false};
        const bool cc[7] = {true, true, true, false, false, false, false};
        const int  cch[7] = {8192, 4096, 2048, 4096, 2048, 512, 512};
        for (int i = 0; i < 7; ++i) {
            if (needOf(cb[i], cc[i], cch[i]) <= ws_size || i == 6) {
                bf = cb[i]; cw = cc[i]; CH = cch[i];
                break;
            }
        }
    }

    float* coeff = (float*)alloc((size_t)B_ * 8 * 4);
    float* muP = (float*)alloc((size_t)B_ * 4);
    float* rsP = (float*)alloc((size_t)B_ * 4);
    unsigned short *xb = nullptr, *hb = nullptr, *shb = nullptr;
    if (bf) {
        xb = (unsigned short*)alloc((size_t)B_ * IN_ * 2);
        hb = (unsigned short*)alloc((size_t)B_ * IN_ * 2);
        shb = (unsigned short*)alloc((size_t)B_ * IN_ * 2);
    }
    unsigned short *Wb = nullptr, *upb[4] = {}, *downb[4] = {}, *domb_ = nullptr,
                   *calb = nullptr, *rg1b = nullptr, *rg2b = nullptr;
    if (cw) {
        Wb = (unsigned short*)alloc((size_t)OUT_ * IN_ * 2);
        domb_ = (unsigned short*)alloc((size_t)4 * OUT_ * IN_ * 2);
        calb = (unsigned short*)alloc((size_t)OUT_ * IN_ * 2);
        rg1b = (unsigned short*)alloc((size_t)512 * IN_ * 2);
        rg2b = (unsigned short*)alloc((size_t)OUT_ * 512 * 2);
        for (int j = 0; j < 4; ++j) {
            upb[j] = (unsigned short*)alloc((size_t)E[j] * IN_ * 2);
            downb[j] = (unsigned short*)alloc((size_t)OUT_ * E[j] * 2);
        }
    }
    unsigned short* U = (unsigned short*)alloc((size_t)CH * 8192 * 2);
    unsigned short* T = (unsigned short*)alloc((size_t)CH * 512 * 2);

    if (cw) {
        cvt(W, Wb, (size_t)OUT_ * IN_, stream);
        for (int j = 0; j < 4; ++j) {
            cvt(up_w[j], upb[j], (size_t)E[j] * IN_, stream);
            cvt(down_w[j], downb[j], (size_t)OUT_ * E[j], stream);
        }
        cvt(dom_ew, domb_, (size_t)4 * OUT_ * IN_, stream);
        cvt(cal_w, calb, (size_t)OUT_ * IN_, stream);
        cvt(rg_w1, rg1b, (size_t)512 * IN_, stream);
        cvt(rg_w2, rg2b, (size_t)OUT_ * 512, stream);
    }

    stats_kernel<<<B_, 256, 0, stream>>>(x, ln_g, ln_b, muP, rsP, xb, hb, shb,
                                         bf ? 1 : 0, bf ? 1 : 0, bf ? 1 : 0);
    router_kernel<<<B_, 256, 0, stream>>>(x, muP, rsP, ln_g, ln_b,
                                          r_w[0], r_b[0], r_w[1], r_b[1], r_w[2], r_b[2],
                                          r_w[3], r_b[3], scales, dom_rw, dom_rb, coeff);

#define GARG(A, BW, OF, OB, BI, CF, CI, SC, MU, NN, KK) \
    (const void*)(A), (const void*)(BW), OF, OB, BI, CF, CI, SC, MU, rsP, ln_g, ln_b, NN, KK
#define LX(ACT, OUTBF, ACCUM, BIASF, GRID, Abf, Af, Bb, Bf, OF, OB, BI, CF, CI, SC, MU, NN, KK)         \
    do {                                                                                                \
        if (bf) {                                                                                       \
            if (cw) gemm_bt<0, 0, 0, ACT, OUTBF, ACCUM, BIASF><<<GRID, 256, 0, stream>>>(               \
                GARG(Abf, Bb, OF, OB, BI, CF, CI, SC, MU, NN, KK));                                     \
            else gemm_bt<0, 0, 1, ACT, OUTBF, ACCUM, BIASF><<<GRID, 256, 0, stream>>>(                  \
                GARG(Abf, Bf, OF, OB, BI, CF, CI, SC, MU, NN, KK));                                     \
        } else gemm_bt<1, 0, 1, ACT, OUTBF, ACCUM, BIASF><<<GRID, 256, 0, stream>>>(                    \
                GARG(Af, Bf, OF, OB, BI, CF, CI, SC, MU, NN, KK));                                      \
    } while (0)
#define LD(ACT, OUTBF, ACCUM, BIASF, GRID, A, Bb, Bf, OF, OB, BI, CF, CI, SC, NN, KK)                   \
    do {                                                                                                \
        if (cw) gemm_bt<0, 0, 0, ACT, OUTBF, ACCUM, BIASF><<<GRID, 256, 0, stream>>>(                   \
            GARG(A, Bb, OF, OB, BI, CF, CI, SC, muP, NN, KK));                                          \
        else gemm_bt<0, 0, 1, ACT, OUTBF, ACCUM, BIASF><<<GRID, 256, 0, stream>>>(                      \
            GARG(A, Bf, OF, OB, BI, CF, CI, SC, muP, NN, KK));                                          \
    } while (0)

    LX(0, 0, 0, 1, dim3(NT_OUT, MT), xb, x, Wb, W, out, nullptr, bvec, (const float*)nullptr, 0,
       (const float*)nullptr, muP, OUT_, IN_);

    for (int k = 0; k < 4; ++k) {
        const unsigned short* Bb = cw ? domb_ + (size_t)k * OUT_ * IN_ : nullptr;
        const float* Bf = dom_ew + (size_t)k * OUT_ * IN_;
        if (bf) {
            if (cw) gemm_bt<0, 0, 0, 0, 0, 1, 0><<<dim3(NT_OUT, MT), 256, 0, stream>>>(
                GARG(shb, Bb, out, nullptr, nullptr, coeff, 4 + k, zeta, muP, OUT_, IN_));
            else gemm_bt<0, 0, 1, 0, 0, 1, 0><<<dim3(NT_OUT, MT), 256, 0, stream>>>(
                GARG(shb, Bf, out, nullptr, nullptr, coeff, 4 + k, zeta, muP, OUT_, IN_));
        } else {
            gemm_bt<2, 1, 1, 0, 0, 1, 0><<<dim3(NT_OUT, MT), 256, 0, stream>>>(
                GARG(x, Bf, out, nullptr, nullptr, coeff, 4 + k, zeta, muP, OUT_, IN_));
        }
    }

    if (bf) {
        if (cw) gemm_bt<0, 0, 0, 5, 0, 1, 1><<<dim3(NT_OUT, MT), 256, 0, stream>>>(
            GARG(hb, calb, out, nullptr, cal_b, nullptr, 0, theta, muP, OUT_, IN_));
        else gemm_bt<0, 0, 1, 5, 0, 1, 1><<<dim3(NT_OUT, MT), 256, 0, stream>>>(
            GARG(hb, cal_w, out, nullptr, cal_b, nullptr, 0, theta, muP, OUT_, IN_));
    } else {
        gemm_bt<2, 0, 1, 5, 0, 1, 1><<<dim3(NT_OUT, MT), 256, 0, stream>>>(
            GARG(x, cal_w, out, nullptr, cal_b, nullptr, 0, theta, muP, OUT_, IN_));
    }

    for (int r0 = 0; r0 < B_; r0 += CH) {
        const int MTC = CH / 128;
        const unsigned short* xbC = bf ? xb + (size_t)r0 * IN_ : nullptr;
        const float* xC = x + (size_t)r0 * IN_;
        float* outC = out + (size_t)r0 * OUT_;
        const float* coeffC = coeff + (size_t)r0 * 8;
        for (int j = 0; j < 4; ++j) {
            dim3 gu(E[j] / 128, MTC);
            if (j == 0)
                LX(1, 1, 0, 0, gu, xbC, xC, upb[0], up_w[0], nullptr, U, nullptr, (const float*)nullptr, 0,
                   (const float*)nullptr, muP, E[0], IN_);
            else if (j == 1)
                LX(2, 1, 0, 0, gu, xbC, xC, upb[1], up_w[1], nullptr, U, nullptr, (const float*)nullptr, 0,
                   (const float*)nullptr, muP, E[1], IN_);
            else if (j == 2)
                LX(3, 1, 0, 0, gu, xbC, xC, upb[2], up_w[2], nullptr, U, nullptr, (const float*)nullptr, 0,
                   (const float*)nullptr, muP, E[2], IN_);
            else
                LX(4, 1, 0, 0, gu, xbC, xC, upb[3], up_w[3], nullptr, U, nullptr, (const float*)nullptr, 0,
                   (const float*)nullptr, muP, E[3], IN_);
            LD(0, 0, 1, 0, dim3(NT_OUT, MTC), U, downb[j], down_w[j], outC, nullptr, nullptr,
               coeffC, j, (const float*)nullptr, OUT_, E[j]);
        }
        LX(1, 1, 0, 0, dim3(4, MTC), xbC, xC, rg1b, rg_w1, nullptr, T, nullptr, (const float*)nullptr, 0,
           (const float*)nullptr, muP, 512, IN_);
        LD(5, 0, 1, 1, dim3(NT_OUT, MTC), T, rg2b, rg_w2, outC, nullptr, rg_b2, nullptr, 0, lam, OUT_, 512);
    }
#undef LX
#undef LD
#undef GARG
}

// Round 13
// 1907.619 us; speedup vs baseline: 1.2048x; 1.0341x over previous
//
#include <hip/hip_runtime.h>
#include <hip/hip_bf16.h>
#include <cstdint>
#include <cstddef>

#define DEVI __device__ __forceinline__

typedef short bf16x8 __attribute__((ext_vector_type(8)));
typedef float f32x4 __attribute__((ext_vector_type(4)));

static constexpr int B_ = 8192;
static constexpr int IN_ = 2048;
static constexpr int OUT_ = 1000;

DEVI float bf2f(unsigned short u) { return __uint_as_float(((unsigned int)u) << 16); }
DEVI unsigned short f2bf(float f) {
    unsigned int x = __float_as_uint(f);
    unsigned int r = x + 0x7FFFu + ((x >> 16) & 1u);
    return (unsigned short)(r >> 16);
}

DEVI void gload16(const unsigned short* g, unsigned short* l) {
    __builtin_amdgcn_global_load_lds((const __attribute__((address_space(1))) void*)g,
                                     (__attribute__((address_space(3))) void*)l, 16, 0, 0);
}

// XCD row-chunk swizzle (proven R3->R4): each XCD owns contiguous row-tiles.
DEVI void xcd_swizzle(int& bx, int& by) {
    const int NX = gridDim.x, NY = gridDim.y;
    if ((NY & 7) == 0) {
        const int NYc = NY >> 3;
        const int d = by * NX + bx;
        const int xcd = d & 7, idx = d >> 3;
        by = xcd * NYc + (idx % NYc);
        bx = idx / NYc;
    }
}

// fast tanh via hw exp: tanh(x) = 1 - 2/(e^{2x}+1), clamped
DEVI float fast_tanh(float x) {
    float xc = fminf(fmaxf(x, -10.f), 10.f);
    float e = __expf(2.f * xc);
    return 1.f - 2.f / (e + 1.f);
}

// ACT: 0=none 1=silu 2=gelu(exact) 3=mish 4=relu 5=tanh
template <int ACT> DEVI float apply_act(float v) {
    if constexpr (ACT == 1) return v / (1.f + __expf(-v));
    else if constexpr (ACT == 2) return 0.5f * v * (1.f + erff(v * 0.70710678118654752f));
    else if constexpr (ACT == 3) {
        float p = __expf(fminf(v, 20.f));
        float sp = (v > 20.f) ? v : __logf(1.f + p);
        return v * fast_tanh(sp);
    } else if constexpr (ACT == 4) return fmaxf(v, 0.f);
    else if constexpr (ACT == 5) return fast_tanh(v);
    else return v;
}

// ---------------- fp32 -> bf16 conversion ----------------
__global__ __launch_bounds__(256) void cvt_kernel(const float* __restrict__ in,
                                                  unsigned short* __restrict__ out, int n4) {
    int stride = gridDim.x * blockDim.x;
    for (int i = blockIdx.x * blockDim.x + threadIdx.x; i < n4; i += stride) {
        float4 v = ((const float4*)in)[i];
        ushort4 o;
        o.x = f2bf(v.x); o.y = f2bf(v.y); o.z = f2bf(v.z); o.w = f2bf(v.w);
        ((ushort4*)out)[i] = o;
    }
}

// dom_experts_w [4*1000][2048] f32 -> padded stacked [4*1024][2048] bf16 (pad rows zero)
__global__ __launch_bounds__(256) void cvt_dom_kernel(const float* __restrict__ in,
                                                      unsigned short* __restrict__ out) {
    const int total = 4096 * (IN_ / 4);
    int stride = gridDim.x * blockDim.x;
    for (int i = blockIdx.x * blockDim.x + threadIdx.x; i < total; i += stride) {
        int orow = i >> 9;
        int oc4 = i & 511;
        int s = orow >> 10, r = orow & 1023;
        ushort4 o = {0, 0, 0, 0};
        if (r < 1000) {
            float4 v = ((const float4*)(in + ((size_t)(s * 1000 + r)) * IN_))[oc4];
            o.x = f2bf(v.x); o.y = f2bf(v.y); o.z = f2bf(v.z); o.w = f2bf(v.w);
        }
        ((ushort4*)out)[i] = o;
    }
}

// ---------------- per-row LN stats (+ optional bf16 materialization) ----------------
__global__ __launch_bounds__(256) void stats_kernel(const float* __restrict__ x,
                                                    const float* __restrict__ g,
                                                    const float* __restrict__ bta,
                                                    float* __restrict__ mu,
                                                    float* __restrict__ rstd,
                                                    unsigned short* __restrict__ xb,
                                                    unsigned short* __restrict__ hb,
                                                    unsigned short* __restrict__ shb,
                                                    const int wX, const int wH, const int wS) {
    const int r = blockIdx.x;
    const int t = threadIdx.x;
    const float* xr = x + (size_t)r * IN_;
    float v[8];
    float s = 0.f, q = 0.f;
#pragma unroll
    for (int i = 0; i < 8; ++i) {
        v[i] = xr[t + i * 256];
        s += v[i];
        q += v[i] * v[i];
    }
#pragma unroll
    for (int off = 32; off > 0; off >>= 1) {
        s += __shfl_down(s, off);
        q += __shfl_down(q, off);
    }
    __shared__ float ss[4], qq[4];
    if ((t & 63) == 0) { ss[t >> 6] = s; qq[t >> 6] = q; }
    __syncthreads();
    s = ss[0] + ss[1] + ss[2] + ss[3];
    q = qq[0] + qq[1] + qq[2] + qq[3];
    const float mean = s * (1.f / IN_);
    const float var = q * (1.f / IN_) - mean * mean;
    const float rs = rsqrtf(var + 1e-5f);
    if (t == 0) { mu[r] = mean; rstd[r] = rs; }
#pragma unroll
    for (int i = 0; i < 8; ++i) {
        int c = t + i * 256;
        if (wX) xb[(size_t)r * IN_ + c] = f2bf(v[i]);
        if (wH | wS) {
            float h = (v[i] - mean) * rs * g[c] + bta[c];
            if (wH) hb[(size_t)r * IN_ + c] = f2bf(h);
            if (wS) shb[(size_t)r * IN_ + c] = f2bf(h / (1.f + __expf(-h)));
        }
    }
}

// ---------------- routers ----------------
__global__ __launch_bounds__(256) void router_kernel(
    const float* __restrict__ x, const float* __restrict__ mu, const float* __restrict__ rstd,
    const float* __restrict__ g, const float* __restrict__ bta,
    const float* __restrict__ rw0, const float* __restrict__ rb0,
    const float* __restrict__ rw1, const float* __restrict__ rb1,
    const float* __restrict__ rw2, const float* __restrict__ rb2,
    const float* __restrict__ rw3, const float* __restrict__ rb3,
    const float* __restrict__ scales, const float* __restrict__ domw,
    const float* __restrict__ domb, float* __restrict__ coeff) {
    const int r = blockIdx.x;
    const int t = threadIdx.x;
    __shared__ float xs[IN_];
    __shared__ float hs[IN_];
    __shared__ float dots[18];
    const float m = mu[r], rs = rstd[r];
#pragma unroll
    for (int i = 0; i < 8; ++i) {
        int c = t + i * 256;
        float xv = x[(size_t)r * IN_ + c];
        xs[c] = xv;
        hs[c] = (xv - m) * rs * g[c] + bta[c];
    }
    __syncthreads();
    const int w = t >> 6, l = t & 63;
    const float* wp[5] = {rw0, rw1, rw2, rw3, domw};
    for (int d = w; d < 18; d += 4) {
        int gidx, row;
        if (d < 2) { gidx = 0; row = d; }
        else if (d < 5) { gidx = 1; row = d - 2; }
        else if (d < 9) { gidx = 2; row = d - 5; }
        else if (d < 14) { gidx = 3; row = d - 9; }
        else { gidx = 4; row = d - 14; }
        const float* wt = wp[gidx] + (size_t)row * IN_;
        const float* src = (gidx == 4) ? hs : xs;
        float p = 0.f;
        for (int i = l; i < IN_; i += 64) p += src[i] * wt[i];
#pragma unroll
        for (int off = 32; off > 0; off >>= 1) p += __shfl_down(p, off);
        if (l == 0) dots[d] = p;
    }
    __syncthreads();
    if (t == 0) {
        const float* rbs[4] = {rb0, rb1, rb2, rb3};
        float c[4] = {0.f, 0.f, 0.f, 0.f};
        int off = 0;
        for (int i = 0; i < 4; ++i) {
            int n = i + 2;
            float lg[5], mx = -1e30f;
            for (int j = 0; j < n; ++j) { lg[j] = dots[off + j] + rbs[i][j]; mx = fmaxf(mx, lg[j]); }
            float den = 0.f;
            for (int j = 0; j < n; ++j) { lg[j] = expf(lg[j] - mx); den += lg[j]; }
            float inv = 1.f / den;
            float sci = scales[i];
            for (int j = 0; j <= i; ++j) c[j] += sci * lg[j] * inv;
            off += n;
        }
        float dl[4], mx = -1e30f;
        for (int k = 0; k < 4; ++k) { dl[k] = dots[14 + k] + domb[k]; mx = fmaxf(mx, dl[k]); }
        float den = 0.f;
        for (int k = 0; k < 4; ++k) { dl[k] = expf(dl[k] - mx); den += dl[k]; }
        float inv = 1.f / den;
        for (int j = 0; j < 4; ++j) coeff[(size_t)r * 8 + j] = c[j];
        for (int k = 0; k < 4; ++k) coeff[(size_t)r * 8 + 4 + k] = dl[k] * inv;
    }
}

// ---------- dom reduce: out[r][c] += zeta * sum_s coeff[r][4+s] * U[r][s*1024+c] ----------
__global__ __launch_bounds__(256) void dom_reduce(
    const unsigned short* __restrict__ U, const float* __restrict__ coeff,
    float* __restrict__ out, const float* __restrict__ zetap) {
    const float zeta = zetap[0];
    const int nGroups = B_ * (OUT_ / 8);  // 8192 * 125
    const int stride = gridDim.x * blockDim.x;
    for (int i = blockIdx.x * blockDim.x + threadIdx.x; i < nGroups; i += stride) {
        const int r = i / 125;
        const int c8 = (i - r * 125) * 8;
        const float w0 = zeta * coeff[(size_t)r * 8 + 4];
        const float w1 = zeta * coeff[(size_t)r * 8 + 5];
        const float w2 = zeta * coeff[(size_t)r * 8 + 6];
        const float w3 = zeta * coeff[(size_t)r * 8 + 7];
        const unsigned short* ur = U + (size_t)r * 4096 + c8;
        bf16x8 p0 = *(const bf16x8*)(ur);
        bf16x8 p1 = *(const bf16x8*)(ur + 1024);
        bf16x8 p2 = *(const bf16x8*)(ur + 2048);
        bf16x8 p3 = *(const bf16x8*)(ur + 3072);
        float* orow = out + (size_t)r * OUT_ + c8;
#pragma unroll
        for (int j = 0; j < 8; ++j) {
            orow[j] += w0 * bf2f((unsigned short)p0[j]) + w1 * bf2f((unsigned short)p1[j]) +
                       w2 * bf2f((unsigned short)p2[j]) + w3 * bf2f((unsigned short)p3[j]);
        }
    }
}

// ============ 256x256 4-sub-phase bf16 GEMM (R10-verified, byte-exact) ============
template <int ACT>
__global__ __launch_bounds__(512, 2) void gemm8p(
    const unsigned short* __restrict__ A, const unsigned short* __restrict__ Bw,
    unsigned short* __restrict__ outB, const int N, const int K) {
    extern __shared__ unsigned short lds[];
    const int t = threadIdx.x;
    const int l = t & 63, w = t >> 6;
    const int wr = w >> 2, wc = w & 3;
    int bx = blockIdx.x, by = blockIdx.y;
    xcd_swizzle(bx, by);
    const int rowBase = by * 256, colBase = bx * 256;

    const int lr = l >> 3;
    const int lcs = (((l & 7) ^ lr) << 3);
    const unsigned short* aSrc[4];
    const unsigned short* bSrc[4];
    int aDst[4], bDst[4];
#pragma unroll
    for (int j = 0; j < 4; ++j) {
        const int h = j >> 1, ci = w * 2 + (j & 1);
        aSrc[j] = A + (size_t)(rowBase + h * 128 + ci * 8 + lr) * K + lcs;
        bSrc[j] = Bw + (size_t)(colBase + h * 128 + ci * 8 + lr) * K + lcs;
        aDst[j] = h * 8192 + ci * 512;
        bDst[j] = 16384 + h * 8192 + ci * 512;
    }

    const int fr = l & 15, fg = l >> 4;
    const int kx0 = ((fg ^ (fr & 7)) << 3);
    const int kx1 = (((4 + fg) ^ (fr & 7)) << 3);
    const int aRow = (wr * 128 + fr) * 64;
    const int bRow = 16384 + (wc * 64 + fr) * 64;

    f32x4 acc[8][4];
#pragma unroll
    for (int m = 0; m < 8; ++m)
#pragma unroll
        for (int n = 0; n < 4; ++n) acc[m][n] = (f32x4){0.f, 0.f, 0.f, 0.f};

    const int nt = K >> 6;

#pragma unroll
    for (int j = 0; j < 4; ++j) gload16(aSrc[j], &lds[aDst[j]]);
#pragma unroll
    for (int j = 0; j < 4; ++j) gload16(bSrc[j], &lds[bDst[j]]);

    bf16x8 aF[4][2], bF[2][2];

#define LOAD_A(mh)                                                                         \
    _Pragma("unroll") for (int m = 0; m < 4; ++m) {                                        \
        aF[m][0] = *(const bf16x8*)&lds[bo + aRow + ((mh)*64 + m * 16) * 64 + kx0];        \
        aF[m][1] = *(const bf16x8*)&lds[bo + aRow + ((mh)*64 + m * 16) * 64 + kx1];        \
    }
#define LOAD_B(nh)                                                                         \
    _Pragma("unroll") for (int n = 0; n < 2; ++n) {                                        \
        bF[n][0] = *(const bf16x8*)&lds[bo + bRow + ((nh)*32 + n * 16) * 64 + kx0];        \
        bF[n][1] = *(const bf16x8*)&lds[bo + bRow + ((nh)*32 + n * 16) * 64 + kx1];        \
    }
#define MFMA_PHASE(mh, nh)                                                                 \
    __builtin_amdgcn_s_setprio(1);                                                         \
    _Pragma("unroll") for (int m = 0; m < 4; ++m)                                          \
        _Pragma("unroll") for (int n = 0; n < 2; ++n) {                                    \
            acc[(mh)*4 + m][(nh)*2 + n] = __builtin_amdgcn_mfma_f32_16x16x32_bf16(         \
                aF[m][0], bF[n][0], acc[(mh)*4 + m][(nh)*2 + n], 0, 0, 0);                 \
            acc[(mh)*4 + m][(nh)*2 + n] = __builtin_amdgcn_mfma_f32_16x16x32_bf16(         \
                aF[m][1], bF[n][1], acc[(mh)*4 + m][(nh)*2 + n], 0, 0, 0);                 \
        }                                                                                  \
    __builtin_amdgcn_s_setprio(0);

    for (int ti = 0; ti < nt; ++ti) {
        const int bo = (ti & 1) << 15;
        const int so = bo ^ 32768;
        const int ko = (ti + 1) << 6;
        const bool pre = (ti + 1 < nt);
        asm volatile("s_waitcnt vmcnt(0)" ::: "memory");
        asm volatile("s_barrier" ::: "memory");
        if (pre) {
#pragma unroll
            for (int j = 0; j < 4; ++j) gload16(aSrc[j] + ko, &lds[so + aDst[j]]);
        }
        LOAD_A(0)
        LOAD_B(0)
        MFMA_PHASE(0, 0)
        asm volatile("s_barrier" ::: "memory");
        if (pre) {
#pragma unroll
            for (int j = 0; j < 4; ++j) gload16(bSrc[j] + ko, &lds[so + bDst[j]]);
        }
        LOAD_A(1)
        MFMA_PHASE(1, 0)
        asm volatile("s_barrier" ::: "memory");
        LOAD_B(1)
        MFMA_PHASE(1, 1)
        asm volatile("s_barrier" ::: "memory");
        LOAD_A(0)
        MFMA_PHASE(0, 1)
    }
#undef LOAD_A
#undef LOAD_B
#undef MFMA_PHASE

#pragma unroll
    for (int m = 0; m < 8; ++m) {
        const int grow0 = rowBase + wr * 128 + m * 16 + fg * 4;
#pragma unroll
        for (int n = 0; n < 4; ++n) {
            const int gcol = colBase + wc * 64 + n * 16 + fr;
#pragma unroll
            for (int j = 0; j < 4; ++j) {
                float v = apply_act<ACT>(acc[m][n][j]);
                outB[(size_t)(grow0 + j) * N + gcol] = f2bf(v);
            }
        }
    }
}

// ============ 128x128 BK=64 GEMM with gemm8p swizzle (R10-verified) ============
// MODE: 0 = write f32 (+bias), 1 = accumulate f32, 2 = write bf16.
template <int ACT, int MODE, int BIASF>
__global__ __launch_bounds__(256) void gemm_bk64(
    const unsigned short* __restrict__ A, const unsigned short* __restrict__ Bw,
    float* __restrict__ outF, unsigned short* __restrict__ outB,
    const float* __restrict__ bias, const float* __restrict__ coeff, const int cidx,
    const float* __restrict__ scalarp, const int N, const int K) {
    __shared__ unsigned short Asm[2][8192];
    __shared__ unsigned short Bsm[2][8192];
    const int t = threadIdx.x;
    const int l = t & 63;
    const int w = t >> 6;
    const int wr = w >> 1, wc = w & 1;
    int bx = blockIdx.x, by = blockIdx.y;
    xcd_swizzle(bx, by);
    const int rowBase = by * 128;
    const int colBase = bx * 128;

    const int lr = l >> 3;
    const int lcs = (((l & 7) ^ lr) << 3);
    const unsigned short* aS[4];
    const unsigned short* bS[4];
    int dst[4];
#pragma unroll
    for (int i = 0; i < 4; ++i) {
        const int r0 = w * 32 + i * 8;
        const int ar = rowBase + r0 + lr;
        int br = colBase + r0 + lr; if (br >= N) br = N - 1;
        aS[i] = A + (size_t)ar * K + lcs;
        bS[i] = Bw + (size_t)br * K + lcs;
        dst[i] = r0 * 64;
    }

    f32x4 acc[4][4];
#pragma unroll
    for (int m = 0; m < 4; ++m)
#pragma unroll
        for (int n = 0; n < 4; ++n) acc[m][n] = (f32x4){0.f, 0.f, 0.f, 0.f};

    const int nK = K >> 6;

    auto stage = [&](int buf, int kt) {
        const int ko = kt << 6;
#pragma unroll
        for (int i = 0; i < 4; ++i) gload16(aS[i] + ko, &Asm[buf][dst[i]]);
#pragma unroll
        for (int i = 0; i < 4; ++i) gload16(bS[i] + ko, &Bsm[buf][dst[i]]);
    };

    stage(0, 0);
    __syncthreads();

    const int fr = l & 15;
    const int fg = l >> 4;
    const int kx0 = ((fg ^ (fr & 7)) << 3);
    const int kx1 = (((4 + fg) ^ (fr & 7)) << 3);

    int buf = 0;
    for (int kt = 0; kt < nK; ++kt) {
        if (kt + 1 < nK) stage(buf ^ 1, kt + 1);
        bf16x8 af[4][2], bfr[4][2];
#pragma unroll
        for (int m = 0; m < 4; ++m) {
            const int ar = (wr * 64 + m * 16 + fr) * 64;
            af[m][0] = *(const bf16x8*)&Asm[buf][ar + kx0];
            af[m][1] = *(const bf16x8*)&Asm[buf][ar + kx1];
        }
#pragma unroll
        for (int n = 0; n < 4; ++n) {
            const int br = (wc * 64 + n * 16 + fr) * 64;
            bfr[n][0] = *(const bf16x8*)&Bsm[buf][br + kx0];
            bfr[n][1] = *(const bf16x8*)&Bsm[buf][br + kx1];
        }
#pragma unroll
        for (int m = 0; m < 4; ++m)
#pragma unroll
            for (int n = 0; n < 4; ++n) {
                acc[m][n] = __builtin_amdgcn_mfma_f32_16x16x32_bf16(af[m][0], bfr[n][0], acc[m][n], 0, 0, 0);
                acc[m][n] = __builtin_amdgcn_mfma_f32_16x16x32_bf16(af[m][1], bfr[n][1], acc[m][n], 0, 0, 0);
            }
        __syncthreads();
        buf ^= 1;
    }

    const float scal = scalarp ? scalarp[0] : 1.0f;
#pragma unroll
    for (int m = 0; m < 4; ++m) {
        const int grow0 = rowBase + wr * 64 + m * 16 + fg * 4;
#pragma unroll
        for (int n = 0; n < 4; ++n) {
            const int gcol = colBase + wc * 64 + n * 16 + fr;
            if (gcol < N) {
                float bv = BIASF ? bias[gcol] : 0.f;
#pragma unroll
                for (int j = 0; j < 4; ++j) {
                    const int grow = grow0 + j;
                    float v = acc[m][n][j] + bv;
                    v = apply_act<ACT>(v);
                    float alpha = scal;
                    if (coeff) alpha *= coeff[(size_t)grow * 8 + cidx];
                    v *= alpha;
                    const size_t o = (size_t)grow * N + gcol;
                    if constexpr (MODE == 2) outB[o] = f2bf(v);
                    else if constexpr (MODE == 1) outF[o] += v;
                    else outF[o] = v;
                }
            }
        }
    }
}

// ---------------- generic (fallback-tier) GEMM: reg-staged, fp32-capable sources ----------------
template <int ASRC, int ASIL, int BSRC, int ACT, int OUTBF, int ACCUM, int BIASF>
__global__ __launch_bounds__(256) void gemm_bt(
    const void* __restrict__ Ap, const void* __restrict__ Bp,
    float* __restrict__ outF, unsigned short* __restrict__ outB,
    const float* __restrict__ bias, const float* __restrict__ coeff, const int cidx,
    const float* __restrict__ scalarp,
    const float* __restrict__ muP, const float* __restrict__ rsP,
    const float* __restrict__ lng, const float* __restrict__ lnb,
    const int N, const int K) {
    __shared__ unsigned short Asm[2][4096];
    __shared__ unsigned short Bsm[2][4096];
    const int t = threadIdx.x;
    const int l = t & 63;
    const int w = t >> 6;
    const int wr = w >> 1, wc = w & 1;
    int bx = blockIdx.x, by = blockIdx.y;
    xcd_swizzle(bx, by);
    const int rowBase = by * 128;
    const int colBase = bx * 128;

    const int srow = t >> 2;
    const int skol = (t & 3) << 3;
    const int arow0 = rowBase + srow;
    const int arow1 = arow0 + 64;
    int br0 = colBase + srow;        if (br0 >= N) br0 = N - 1;
    int br1 = colBase + srow + 64;   if (br1 >= N) br1 = N - 1;

    float mu0 = 0.f, rs0 = 1.f, mu1 = 0.f, rs1 = 1.f;
    if constexpr (ASRC == 2) {
        mu0 = muP[arow0]; rs0 = rsP[arow0];
        mu1 = muP[arow1]; rs1 = rsP[arow1];
    }

    auto ldA = [&](int row, float mu_, float rs_, int k0) -> bf16x8 {
        if constexpr (ASRC == 0) {
            bf16x8 v = *(const bf16x8*)((const unsigned short*)Ap + (size_t)row * K + k0);
            if constexpr (ASIL) {
                bf16x8 r;
#pragma unroll
                for (int i = 0; i < 8; ++i) {
                    float f = bf2f((unsigned short)v[i]);
                    r[i] = (short)f2bf(f / (1.f + __expf(-f)));
                }
                return r;
            }
            return v;
        } else {
            const float* f = (const float*)Ap + (size_t)row * K + k0;
            float4 v0 = *(const float4*)f;
            float4 v1 = *(const float4*)(f + 4);
            float vv[8] = {v0.x, v0.y, v0.z, v0.w, v1.x, v1.y, v1.z, v1.w};
            if constexpr (ASRC == 2) {
                float4 g0 = *(const float4*)(lng + k0), g1 = *(const float4*)(lng + k0 + 4);
                float4 b0 = *(const float4*)(lnb + k0), b1 = *(const float4*)(lnb + k0 + 4);
                float gg[8] = {g0.x, g0.y, g0.z, g0.w, g1.x, g1.y, g1.z, g1.w};
                float bb[8] = {b0.x, b0.y, b0.z, b0.w, b1.x, b1.y, b1.z, b1.w};
#pragma unroll
                for (int i = 0; i < 8; ++i) vv[i] = (vv[i] - mu_) * rs_ * gg[i] + bb[i];
            }
            if constexpr (ASIL) {
#pragma unroll
                for (int i = 0; i < 8; ++i) vv[i] = vv[i] / (1.f + __expf(-vv[i]));
            }
            bf16x8 r;
#pragma unroll
            for (int i = 0; i < 8; ++i) r[i] = (short)f2bf(vv[i]);
            return r;
        }
    };
    auto ldB = [&](int row, int k0) -> bf16x8 {
        if constexpr (BSRC == 0) {
            return *(const bf16x8*)((const unsigned short*)Bp + (size_t)row * K + k0);
        } else {
            const float* f = (const float*)Bp + (size_t)row * K + k0;
            float4 v0 = *(const float4*)f;
            float4 v1 = *(const float4*)(f + 4);
            float vv[8] = {v0.x, v0.y, v0.z, v0.w, v1.x, v1.y, v1.z, v1.w};
            bf16x8 r;
#pragma unroll
            for (int i = 0; i < 8; ++i) r[i] = (short)f2bf(vv[i]);
            return r;
        }
    };

    const int wo = t * 8;

    f32x4 acc[4][4];
#pragma unroll
    for (int m = 0; m < 4; ++m)
#pragma unroll
        for (int n = 0; n < 4; ++n) acc[m][n] = (f32x4){0.f, 0.f, 0.f, 0.f};

    const int nK = K >> 5;

    bf16x8 a0 = ldA(arow0, mu0, rs0, skol);
    bf16x8 a1 = ldA(arow1, mu1, rs1, skol);
    bf16x8 b0 = ldB(br0, skol);
    bf16x8 b1 = ldB(br1, skol);
    *(bf16x8*)&Asm[0][wo] = a0; *(bf16x8*)&Asm[0][wo + 2048] = a1;
    *(bf16x8*)&Bsm[0][wo] = b0; *(bf16x8*)&Bsm[0][wo + 2048] = b1;
    __syncthreads();

    const int fr = l & 15;
    const int fg = l >> 4;
    const int aoff = (wr * 64 + fr) * 32 + fg * 8;
    const int boff = (wc * 64 + fr) * 32 + fg * 8;

    for (int kt = 0; kt < nK; ++kt) {
        const int cur = kt & 1;
        if (kt + 1 < nK) {
            const int ko = ((kt + 1) << 5) + skol;
            a0 = ldA(arow0, mu0, rs0, ko);
            a1 = ldA(arow1, mu1, rs1, ko);
            b0 = ldB(br0, ko);
            b1 = ldB(br1, ko);
        }
        bf16x8 af[4], bfr[4];
#pragma unroll
        for (int m = 0; m < 4; ++m) af[m] = *(const bf16x8*)&Asm[cur][aoff + m * 512];
#pragma unroll
        for (int n = 0; n < 4; ++n) bfr[n] = *(const bf16x8*)&Bsm[cur][boff + n * 512];
#pragma unroll
        for (int m = 0; m < 4; ++m)
#pragma unroll
            for (int n = 0; n < 4; ++n)
                acc[m][n] = __builtin_amdgcn_mfma_f32_16x16x32_bf16(af[m], bfr[n], acc[m][n], 0, 0, 0);
        if (kt + 1 < nK) {
            __syncthreads();
            const int nxt = cur ^ 1;
            *(bf16x8*)&Asm[nxt][wo] = a0; *(bf16x8*)&Asm[nxt][wo + 2048] = a1;
            *(bf16x8*)&Bsm[nxt][wo] = b0; *(bf16x8*)&Bsm[nxt][wo + 2048] = b1;
            __syncthreads();
        }
    }

    const float scal = scalarp ? scalarp[0] : 1.0f;
#pragma unroll
    for (int m = 0; m < 4; ++m) {
        const int grow0 = rowBase + wr * 64 + m * 16 + fg * 4;
#pragma unroll
        for (int n = 0; n < 4; ++n) {
            const int gcol = colBase + wc * 64 + n * 16 + fr;
            if (gcol < N) {
                float bv = BIASF ? bias[gcol] : 0.f;
#pragma unroll
                for (int j = 0; j < 4; ++j) {
                    const int grow = grow0 + j;
                    float v = acc[m][n][j] + bv;
                    v = apply_act<ACT>(v);
                    float alpha = scal;
                    if (coeff) alpha *= coeff[(size_t)grow * 8 + cidx];
                    v *= alpha;
                    const size_t o = (size_t)grow * N + gcol;
                    if (OUTBF) outB[o] = f2bf(v);
                    else if (ACCUM) outF[o] += v;
                    else outF[o] = v;
                }
            }
        }
    }
}

static inline void cvt(const float* in, unsigned short* out, size_t n, hipStream_t s) {
    int n4 = (int)(n >> 2);
    int blocks = (n4 + 255) / 256;
    if (blocks > 4096) blocks = 4096;
    cvt_kernel<<<blocks, 256, 0, s>>>(in, out, n4);
}

extern "C" void kernel_launch(void* const* d_in, const int* in_sizes, int n_in,
                              void* d_out, int out_size, void* d_ws, size_t ws_size,
                              hipStream_t stream) {
    (void)in_sizes; (void)n_in; (void)out_size;
    const float* x = (const float*)d_in[0];
    const float* W = (const float*)d_in[1];
    const float* bvec = (const float*)d_in[2];
    const float* up_w[4] = {(const float*)d_in[3], (const float*)d_in[7], (const float*)d_in[11], (const float*)d_in[15]};
    const float* down_w[4] = {(const float*)d_in[4], (const float*)d_in[8], (const float*)d_in[12], (const float*)d_in[16]};
    const float* r_w[4] = {(const float*)d_in[5], (const float*)d_in[9], (const float*)d_in[13], (const float*)d_in[17]};
    const float* r_b[4] = {(const float*)d_in[6], (const float*)d_in[10], (const float*)d_in[14], (const float*)d_in[18]};
    const float* scales = (const float*)d_in[19];
    const float* ln_g = (const float*)d_in[20];
    const float* ln_b = (const float*)d_in[21];
    const float* dom_rw = (const float*)d_in[22];
    const float* dom_rb = (const float*)d_in[23];
    const float* dom_ew = (const float*)d_in[24];
    const float* cal_w = (const float*)d_in[25];
    const float* cal_b = (const float*)d_in[26];
    const float* rg_w1 = (const float*)d_in[27];
    const float* rg_w2 = (const float*)d_in[28];
    const float* rg_b2 = (const float*)d_in[29];
    const float* zeta = (const float*)d_in[30];
    const float* theta = (const float*)d_in[31];
    const float* lam = (const float*)d_in[32];
    float* out = (float*)d_out;

    const int E[4] = {2048, 4096, 6144, 8192};
    auto al = [](size_t v) { return (v + 255) & ~(size_t)255; };

    size_t fastNeed = al((size_t)B_ * 8 * 4) + 2 * al((size_t)B_ * 4) +
                      2 * al((size_t)B_ * IN_ * 2) +
                      al((size_t)OUT_ * IN_ * 2) +
                      al((size_t)4096 * IN_ * 2) +
                      al((size_t)OUT_ * IN_ * 2) +
                      al((size_t)512 * IN_ * 2) + al((size_t)OUT_ * 512 * 2) +
                      al((size_t)B_ * 8192 * 2) + al((size_t)B_ * 512 * 2);
    for (int j = 0; j < 4; ++j)
        fastNeed += al((size_t)E[j] * IN_ * 2) + al((size_t)OUT_ * E[j] * 2);

    char* p = (char*)d_ws;
    auto alloc = [&](size_t bytes) { char* r = p; p += (bytes + 255) & ~(size_t)255; return r; };

    const int NT_OUT = (OUT_ + 127) / 128;  // 8
    const int MT = B_ / 128;                // 64

    if (ws_size >= fastNeed) {
        // ================= FAST PATH (R10-verified; dom stage-1 -> gemm_bk64) =================
        float* coeff = (float*)alloc((size_t)B_ * 8 * 4);
        float* muP = (float*)alloc((size_t)B_ * 4);
        float* rsP = (float*)alloc((size_t)B_ * 4);
        unsigned short* xb = (unsigned short*)alloc((size_t)B_ * IN_ * 2);
        unsigned short* shb = (unsigned short*)alloc((size_t)B_ * IN_ * 2);
        unsigned short* Wb = (unsigned short*)alloc((size_t)OUT_ * IN_ * 2);
        unsigned short* domN = (unsigned short*)alloc((size_t)4096 * IN_ * 2);
        unsigned short* calb = (unsigned short*)alloc((size_t)OUT_ * IN_ * 2);
        unsigned short* rg1b = (unsigned short*)alloc((size_t)512 * IN_ * 2);
        unsigned short* rg2b = (unsigned short*)alloc((size_t)OUT_ * 512 * 2);
        unsigned short* U = (unsigned short*)alloc((size_t)B_ * 8192 * 2);
        unsigned short* T = (unsigned short*)alloc((size_t)B_ * 512 * 2);
        unsigned short* upb[4];
        unsigned short* downb[4];
        for (int j = 0; j < 4; ++j) {
            upb[j] = (unsigned short*)alloc((size_t)E[j] * IN_ * 2);
            downb[j] = (unsigned short*)alloc((size_t)OUT_ * E[j] * 2);
        }
        unsigned short* hbU = U;  // h bf16 borrows U until dom-partial overwrites it

        hipFuncSetAttribute((const void*)gemm8p<1>, hipFuncAttributeMaxDynamicSharedMemorySize, 131072);
        hipFuncSetAttribute((const void*)gemm8p<2>, hipFuncAttributeMaxDynamicSharedMemorySize, 131072);
        hipFuncSetAttribute((const void*)gemm8p<3>, hipFuncAttributeMaxDynamicSharedMemorySize, 131072);
        hipFuncSetAttribute((const void*)gemm8p<4>, hipFuncAttributeMaxDynamicSharedMemorySize, 131072);

        // weight conversions
        cvt(W, Wb, (size_t)OUT_ * IN_, stream);
        cvt_dom_kernel<<<4096, 256, 0, stream>>>(dom_ew, domN);
        cvt(cal_w, calb, (size_t)OUT_ * IN_, stream);
        cvt(rg_w1, rg1b, (size_t)512 * IN_, stream);
        cvt(rg_w2, rg2b, (size_t)OUT_ * 512, stream);
        for (int j = 0; j < 4; ++j) {
            cvt(up_w[j], upb[j], (size_t)E[j] * IN_, stream);
            cvt(down_w[j], downb[j], (size_t)OUT_ * E[j], stream);
        }

        // stats (xb, h -> U scratch, silu(h)) + router coeffs
        stats_kernel<<<B_, 256, 0, stream>>>(x, ln_g, ln_b, muP, rsP, xb, hbU, shb, 1, 1, 1);
        router_kernel<<<B_, 256, 0, stream>>>(x, muP, rsP, ln_g, ln_b,
                                              r_w[0], r_b[0], r_w[1], r_b[1], r_w[2], r_b[2],
                                              r_w[3], r_b[3], scales, dom_rw, dom_rb, coeff);

        // base: out = x @ W^T + b (full write, clears poison)
        gemm_bk64<0, 0, 1><<<dim3(NT_OUT, MT), 256, 0, stream>>>(
            xb, Wb, out, nullptr, bvec, nullptr, 0, nullptr, OUT_, IN_);

        // calib: out += theta * tanh(h @ calib^T + calib_b)  (reads h from U, before dom clobbers)
        gemm_bk64<5, 1, 1><<<dim3(NT_OUT, MT), 256, 0, stream>>>(
            hbU, calb, out, nullptr, cal_b, nullptr, 0, theta, OUT_, IN_);

        // dom stage 1: partials U[8192][4096] = shb @ domN^T  (BK64+swizzle kernel)
        gemm_bk64<0, 2, 0><<<dim3(32, MT), 256, 0, stream>>>(
            shb, domN, nullptr, U, nullptr, nullptr, 0, nullptr, 4096, IN_);
        // dom stage 2: out += zeta * sum_s w_s[row] * U[row][s*1024+c]
        dom_reduce<<<2048, 256, 0, stream>>>(U, coeff, out, zeta);

        // branches: U = act_j(x @ up_j^T) via 256^2 kernel; downs accumulate (BK64)
        gemm8p<1><<<dim3(E[0] / 256, B_ / 256), 512, 131072, stream>>>(xb, upb[0], U, E[0], IN_);
        gemm_bk64<0, 1, 0><<<dim3(NT_OUT, MT), 256, 0, stream>>>(
            U, downb[0], out, nullptr, nullptr, coeff, 0, nullptr, OUT_, E[0]);
        gemm8p<2><<<dim3(E[1] / 256, B_ / 256), 512, 131072, stream>>>(xb, upb[1], U, E[1], IN_);
        gemm_bk64<0, 1, 0><<<dim3(NT_OUT, MT), 256, 0, stream>>>(
            U, downb[1], out, nullptr, nullptr, coeff, 1, nullptr, OUT_, E[1]);
        gemm8p<3><<<dim3(E[2] / 256, B_ / 256), 512, 131072, stream>>>(xb, upb[2], U, E[2], IN_);
        gemm_bk64<0, 1, 0><<<dim3(NT_OUT, MT), 256, 0, stream>>>(
            U, downb[2], out, nullptr, nullptr, coeff, 2, nullptr, OUT_, E[2]);
        gemm8p<4><<<dim3(E[3] / 256, B_ / 256), 512, 131072, stream>>>(xb, upb[3], U, E[3], IN_);
        gemm_bk64<0, 1, 0><<<dim3(NT_OUT, MT), 256, 0, stream>>>(
            U, downb[3], out, nullptr, nullptr, coeff, 3, nullptr, OUT_, E[3]);

        // reason: T = silu(x @ rg1^T); out += lambda * tanh(T @ rg2^T + rg_b2)
        gemm_bk64<1, 2, 0><<<dim3(4, MT), 256, 0, stream>>>(
            xb, rg1b, nullptr, T, nullptr, nullptr, 0, nullptr, 512, IN_);
        gemm_bk64<5, 1, 1><<<dim3(NT_OUT, MT), 256, 0, stream>>>(
            T, rg2b, out, nullptr, rg_b2, nullptr, 0, lam, OUT_, 512);
        return;
    }

    // ================= FALLBACK TIERS (verified R2 path) =================
    const size_t S_coeff = al((size_t)B_ * 8 * 4);
    const size_t S_mu = al((size_t)B_ * 4);
    const size_t S_act = al((size_t)B_ * IN_ * 2);
    size_t S_W = al((size_t)OUT_ * IN_ * 2) + al((size_t)4 * OUT_ * IN_ * 2) +
                 al((size_t)OUT_ * IN_ * 2) + al((size_t)512 * IN_ * 2) + al((size_t)OUT_ * 512 * 2);
    for (int j = 0; j < 4; ++j) S_W += al((size_t)E[j] * IN_ * 2) + al((size_t)OUT_ * E[j] * 2);

    auto needOf = [&](bool bfl, bool cwl, int ch) {
        size_t n = S_coeff + 2 * S_mu;
        if (bfl) n += 3 * S_act;
        if (cwl) n += S_W;
        n += al((size_t)ch * 8192 * 2) + al((size_t)ch * 512 * 2);
        return n;
    };
    bool bf = false, cw = false;
    int CH = 512;
    {
        const bool cb[7] = {true, true, true, true, true, true, false};
        const bool cc[7] = {true, true, true, false, false, false, false};
        const int  cch[7] = {8192, 4096, 2048, 4096, 2048, 512, 512};
        for (int i = 0; i < 7; ++i) {
            if (needOf(cb[i], cc[i], cch[i]) <= ws_size || i == 6) {
                bf = cb[i]; cw = cc[i]; CH = cch[i];
                break;
            }
        }
    }

    float* coeff = (float*)alloc((size_t)B_ * 8 * 4);
    float* muP = (float*)alloc((size_t)B_ * 4);
    float* rsP = (float*)alloc((size_t)B_ * 4);
    unsigned short *xb = nullptr, *hb = nullptr, *shb = nullptr;
    if (bf) {
        xb = (unsigned short*)alloc((size_t)B_ * IN_ * 2);
        hb = (unsigned short*)alloc((size_t)B_ * IN_ * 2);
        shb = (unsigned short*)alloc((size_t)B_ * IN_ * 2);
    }
    unsigned short *Wb = nullptr, *upb[4] = {}, *downb[4] = {}, *domb_ = nullptr,
                   *calb = nullptr, *rg1b = nullptr, *rg2b = nullptr;
    if (cw) {
        Wb = (unsigned short*)alloc((size_t)OUT_ * IN_ * 2);
        domb_ = (unsigned short*)alloc((size_t)4 * OUT_ * IN_ * 2);
        calb = (unsigned short*)alloc((size_t)OUT_ * IN_ * 2);
        rg1b = (unsigned short*)alloc((size_t)512 * IN_ * 2);
        rg2b = (unsigned short*)alloc((size_t)OUT_ * 512 * 2);
        for (int j = 0; j < 4; ++j) {
            upb[j] = (unsigned short*)alloc((size_t)E[j] * IN_ * 2);
            downb[j] = (unsigned short*)alloc((size_t)OUT_ * E[j] * 2);
        }
    }
    unsigned short* U = (unsigned short*)alloc((size_t)CH * 8192 * 2);
    unsigned short* T = (unsigned short*)alloc((size_t)CH * 512 * 2);

    if (cw) {
        cvt(W, Wb, (size_t)OUT_ * IN_, stream);
        for (int j = 0; j < 4; ++j) {
            cvt(up_w[j], upb[j], (size_t)E[j] * IN_, stream);
            cvt(down_w[j], downb[j], (size_t)OUT_ * E[j], stream);
        }
        cvt(dom_ew, domb_, (size_t)4 * OUT_ * IN_, stream);
        cvt(cal_w, calb, (size_t)OUT_ * IN_, stream);
        cvt(rg_w1, rg1b, (size_t)512 * IN_, stream);
        cvt(rg_w2, rg2b, (size_t)OUT_ * 512, stream);
    }

    stats_kernel<<<B_, 256, 0, stream>>>(x, ln_g, ln_b, muP, rsP, xb, hb, shb,
                                         bf ? 1 : 0, bf ? 1 : 0, bf ? 1 : 0);
    router_kernel<<<B_, 256, 0, stream>>>(x, muP, rsP, ln_g, ln_b,
                                          r_w[0], r_b[0], r_w[1], r_b[1], r_w[2], r_b[2],
                                          r_w[3], r_b[3], scales, dom_rw, dom_rb, coeff);

#define GARG(A, BW, OF, OB, BI, CF, CI, SC, MU, NN, KK) \
    (const void*)(A), (const void*)(BW), OF, OB, BI, CF, CI, SC, MU, rsP, ln_g, ln_b, NN, KK
#define LX(ACT, OUTBF, ACCUM, BIASF, GRID, Abf, Af, Bb, Bf, OF, OB, BI, CF, CI, SC, MU, NN, KK)         \
    do {                                                                                                \
        if (bf) {                                                                                       \
            if (cw) gemm_bt<0, 0, 0, ACT, OUTBF, ACCUM, BIASF><<<GRID, 256, 0, stream>>>(               \
                GARG(Abf, Bb, OF, OB, BI, CF, CI, SC, MU, NN, KK));                                     \
            else gemm_bt<0, 0, 1, ACT, OUTBF, ACCUM, BIASF><<<GRID, 256, 0, stream>>>(                  \
                GARG(Abf, Bf, OF, OB, BI, CF, CI, SC, MU, NN, KK));                                     \
        } else gemm_bt<1, 0, 1, ACT, OUTBF, ACCUM, BIASF><<<GRID, 256, 0, stream>>>(                    \
                GARG(Af, Bf, OF, OB, BI, CF, CI, SC, MU, NN, KK));                                      \
    } while (0)
#define LD(ACT, OUTBF, ACCUM, BIASF, GRID, A, Bb, Bf, OF, OB, BI, CF, CI, SC, NN, KK)                   \
    do {                                                                                                \
        if (cw) gemm_bt<0, 0, 0, ACT, OUTBF, ACCUM, BIASF><<<GRID, 256, 0, stream>>>(                   \
            GARG(A, Bb, OF, OB, BI, CF, CI, SC, muP, NN, KK));                                          \
        else gemm_bt<0, 0, 1, ACT, OUTBF, ACCUM, BIASF><<<GRID, 256, 0, stream>>>(                      \
            GARG(A, Bf, OF, OB, BI, CF, CI, SC, muP, NN, KK));                                          \
    } while (0)

    LX(0, 0, 0, 1, dim3(NT_OUT, MT), xb, x, Wb, W, out, nullptr, bvec, (const float*)nullptr, 0,
       (const float*)nullptr, muP, OUT_, IN_);

    for (int k = 0; k < 4; ++k) {
        const unsigned short* Bb = cw ? domb_ + (size_t)k * OUT_ * IN_ : nullptr;
        const float* Bf = dom_ew + (size_t)k * OUT_ * IN_;
        if (bf) {
            if (cw) gemm_bt<0, 0, 0, 0, 0, 1, 0><<<dim3(NT_OUT, MT), 256, 0, stream>>>(
                GARG(shb, Bb, out, nullptr, nullptr, coeff, 4 + k, zeta, muP, OUT_, IN_));
            else gemm_bt<0, 0, 1, 0, 0, 1, 0><<<dim3(NT_OUT, MT), 256, 0, stream>>>(
                GARG(shb, Bf, out, nullptr, nullptr, coeff, 4 + k, zeta, muP, OUT_, IN_));
        } else {
            gemm_bt<2, 1, 1, 0, 0, 1, 0><<<dim3(NT_OUT, MT), 256, 0, stream>>>(
                GARG(x, Bf, out, nullptr, nullptr, coeff, 4 + k, zeta, muP, OUT_, IN_));
        }
    }

    if (bf) {
        if (cw) gemm_bt<0, 0, 0, 5, 0, 1, 1><<<dim3(NT_OUT, MT), 256, 0, stream>>>(
            GARG(hb, calb, out, nullptr, cal_b, nullptr, 0, theta, muP, OUT_, IN_));
        else gemm_bt<0, 0, 1, 5, 0, 1, 1><<<dim3(NT_OUT, MT), 256, 0, stream>>>(
            GARG(hb, cal_w, out, nullptr, cal_b, nullptr, 0, theta, muP, OUT_, IN_));
    } else {
        gemm_bt<2, 0, 1, 5, 0, 1, 1><<<dim3(NT_OUT, MT), 256, 0, stream>>>(
            GARG(x, cal_w, out, nullptr, cal_b, nullptr, 0, theta, muP, OUT_, IN_));
    }

    for (int r0 = 0; r0 < B_; r0 += CH) {
        const int MTC = CH / 128;
        const unsigned short* xbC = bf ? xb + (size_t)r0 * IN_ : nullptr;
        const float* xC = x + (size_t)r0 * IN_;
        float* outC = out + (size_t)r0 * OUT_;
        const float* coeffC = coeff + (size_t)r0 * 8;
        for (int j = 0; j < 4; ++j) {
            dim3 gu(E[j] / 128, MTC);
            if (j == 0)
                LX(1, 1, 0, 0, gu, xbC, xC, upb[0], up_w[0], nullptr, U, nullptr, (const float*)nullptr, 0,
                   (const float*)nullptr, muP, E[0], IN_);
            else if (j == 1)
                LX(2, 1, 0, 0, gu, xbC, xC, upb[1], up_w[1], nullptr, U, nullptr, (const float*)nullptr, 0,
                   (const float*)nullptr, muP, E[1], IN_);
            else if (j == 2)
                LX(3, 1, 0, 0, gu, xbC, xC, upb[2], up_w[2], nullptr, U, nullptr, (const float*)nullptr, 0,
                   (const float*)nullptr, muP, E[2], IN_);
            else
                LX(4, 1, 0, 0, gu, xbC, xC, upb[3], up_w[3], nullptr, U, nullptr, (const float*)nullptr, 0,
                   (const float*)nullptr, muP, E[3], IN_);
            LD(0, 0, 1, 0, dim3(NT_OUT, MTC), U, downb[j], down_w[j], outC, nullptr, nullptr,
               coeffC, j, (const float*)nullptr, OUT_, E[j]);
        }
        LX(1, 1, 0, 0, dim3(4, MTC), xbC, xC, rg1b, rg_w1, nullptr, T, nullptr, (const float*)nullptr, 0,
           (const float*)nullptr, muP, 512, IN_);
        LD(5, 0, 1, 1, dim3(NT_OUT, MTC), T, rg2b, rg_w2, outC, nullptr, rg_b2, nullptr, 0, lam, OUT_, 512);
    }
#undef LX
#undef LD
#undef GARG
}